// Round 9
// baseline (20013.698 us; speedup 1.0000x reference)
//
#include <hip/hip_runtime.h>
#include <hip/hip_cooperative_groups.h>

namespace cg = cooperative_groups;

typedef __bf16 bf16;
typedef __attribute__((ext_vector_type(8))) __bf16 bf16x8;
typedef __attribute__((ext_vector_type(4))) __bf16 bf16x4;
typedef __attribute__((ext_vector_type(4))) float f32x4;
typedef __attribute__((ext_vector_type(4))) int i32x4;

#define B_TOT 16384
#define SEQ 50
#define DH 512
#define ZW 2048  // 4*DH
#define NT 16    // K-tiles of 32 (K = 512)
#define NBLK 768    // persistent grid: 3 blocks/CU x 256 CUs
#define NGEMM 4096  // 128 bx * 16 by * 2 bz
#define NITEM 4352  // + 256 heads chunks (64 rows each)

#define MFMA16(a, b, c) __builtin_amdgcn_mfma_f32_16x16x32_bf16(a, b, c, 0, 0, 0)

__device__ __forceinline__ float fsigm(float x) {
    return __fdividef(1.0f, 1.0f + __expf(-x));
}
__device__ __forceinline__ float ftanh(float x) {
    float e = __expf(2.0f * x);
    return 1.0f - __fdividef(2.0f, e + 1.0f);
}

// ---------------------------------------------------------------------------
// Fragment layout (both GEMM operands):
//   frag[((rg*16 + kt)*64 + fq*16 + fr)]*8 + e <-> element [rg*16+fr][kt*32+fq*8+e]
// Strides: rg = 16384 B, kt = 1024 B, lane-slot = 16 B.
// ---------------------------------------------------------------------------

__global__ void init_state(const float* __restrict__ sh,
                           bf16* __restrict__ h0m, bf16* __restrict__ h0y) {
    size_t i = (size_t)blockIdx.x * 256 + threadIdx.x;
    int row = i >> 9, k = i & 511;
    size_t off = (((size_t)(row >> 4) * 16 + (k >> 5)) * 64 + ((k >> 3) & 3) * 16 +
                  (row & 15)) * 8 + (k & 7);
    bf16 hb = (bf16)sh[i];
    h0m[off] = hb;
    h0y[off] = hb;
}

// c3[row>>2][hcol][row&3] f32, duplicated into cM and cY.
__global__ void build_c3(const float* __restrict__ src,
                         float* __restrict__ dM, float* __restrict__ dY) {
    size_t i = (size_t)blockIdx.x * 256 + threadIdx.x;
    int row = i >> 9, hcol = i & 511;
    float v = src[i];
    size_t o = ((size_t)(row >> 2) * 512 + hcol) * 4 + (row & 3);
    dM[o] = v;
    dY[o] = v;
}

__device__ __forceinline__ int orig_col(int colp) {
    return ((colp >> 4) & 3) * 512 + ((colp >> 6) << 4) + (colp & 15);
}

// B-operands (U^T, W^T) in fragment layout.
__global__ void reorder_weights(const float* __restrict__ Um, const float* __restrict__ Uy,
                                const float* __restrict__ Wm, const float* __restrict__ Wy,
                                bf16* __restrict__ UtM, bf16* __restrict__ UtY,
                                bf16* __restrict__ WtM, bf16* __restrict__ WtY) {
    int idx = blockIdx.x * 256 + threadIdx.x;
    int which = idx >> 20;
    int r = idx & ((1 << 20) - 1);
    int colp = r >> 9, k = r & 511;
    int orig = orig_col(colp);
    const float* src = which == 0 ? Um : which == 1 ? Uy : which == 2 ? Wm : Wy;
    bf16* dst = which == 0 ? UtM : which == 1 ? UtY : which == 2 ? WtM : WtY;
    int cb = colp >> 4, fr = colp & 15;
    int kt = k >> 5, fq = (k >> 3) & 3, e = k & 7;
    int lane = fq * 16 + fr;
    dst[(((size_t)(cb * 16 + kt) * 64 + lane) << 3) + e] = (bf16)src[(size_t)k * ZW + orig];
}

// Wc2[hcol][r(3)][g(4)] f32
__global__ void build_wc2(const float* __restrict__ Wm, const float* __restrict__ Wy,
                          float* __restrict__ Wc2M, float* __restrict__ Wc2Y) {
    int idx = blockIdx.x * 256 + threadIdx.x;
    if (idx >= 2 * 512 * 12) return;
    int which = idx / 6144;
    int r2 = idx % 6144;
    int hcol = r2 / 12, rg = r2 % 12;
    int r = rg >> 2, g = rg & 3;
    const float* src = which ? Wy : Wm;
    float* dst = which ? Wc2Y : Wc2M;
    dst[hcol * 12 + rg] = src[(size_t)(512 + r) * ZW + g * 512 + hcol];
}

// condT4[t][row][4] f32
__global__ void cond_transpose(const float* __restrict__ cond, float* __restrict__ condT4) {
    int idx = blockIdx.x * 256 + threadIdx.x;
    if (idx >= SEQ * B_TOT) return;
    int t = idx / B_TOT, row = idx % B_TOT;
    const float* s = cond + ((size_t)row * SEQ + t) * 3;
    f32x4 v = {s[0], s[1], s[2], 0.f};
    *(f32x4*)(condT4 + (size_t)idx * 4) = v;
}

__global__ void build_heads(const float* __restrict__ Whm, const float* __restrict__ bhm,
                            const float* __restrict__ Why, const float* __restrict__ bhy,
                            bf16* __restrict__ WhmT, bf16* __restrict__ WhyT,
                            float* __restrict__ tscm, float* __restrict__ tscy) {
    int i = blockIdx.x * 256 + threadIdx.x;
    const int N1 = 32 * 512, N2 = 16 * 512, N3 = SEQ * 32, N4 = SEQ * 16;
    if (i < N1) {
        int n = i >> 9, k = i & 511;
        WhmT[i] = (bf16)(n < 30 ? Whm[k * 30 + n] : 0.f);
    } else if (i < N1 + N2) {
        int j = i - N1;
        int n = j >> 9, k = j & 511;
        WhyT[j] = (bf16)(n < 15 ? Why[k * 15 + n] : 0.f);
    } else if (i < N1 + N2 + N3) {
        int j = i - (N1 + N2);
        int tt = j >> 5, col = j & 31;
        float v = 0.f;
        if (col < 30) {
            v = bhm[col];
            for (int s = 0; s <= tt; ++s) v += Whm[(512 + s) * 30 + col];
        }
        tscm[j] = v;
    } else if (i < N1 + N2 + N3 + N4) {
        int j = i - (N1 + N2 + N3);
        int tt = j >> 4, col = j & 15;
        float v = 0.f;
        if (col < 15) {
            v = bhy[col];
            for (int s = 0; s <= tt; ++s) v += Why[(512 + s) * 15 + col];
        }
        tscy[j] = v;
    }
}

// ---------------------------------------------------------------------------
// Decoder work items.
// ---------------------------------------------------------------------------

struct DecP {
    bf16 *hM0, *hM1, *hY0, *hY1;
    const bf16 *UtM, *UtY, *WtM, *WtY;
    bf16 *xwM, *xwY;
    const float *Wc2M, *Wc2Y, *bm, *by_;
    float *cM, *cY;
    const float* condT4;
    const bf16 *WhmT, *WhyT;
    const float *tscm, *tscy;
    float* out;
};

#define WAIT_VM(n)                                                  \
    do {                                                            \
        asm volatile("s_waitcnt vmcnt(" #n ")" ::: "memory");       \
        __builtin_amdgcn_sched_barrier(0);                          \
    } while (0)

// gemm item: 128x128 tile, BK=32, 4 waves (2x2), no LDS, no barriers;
// reg double-buffered fragment loads, counted vmcnt(8).
template <int MODE>
__device__ __forceinline__ void gemm_item(const DecP& P, int item, int t) {
    const int tid = threadIdx.x;
    const int wave = tid >> 6, lane = tid & 63;
    const int bz = item >> 11;
    const int lin = item & 2047;
    const int bx = lin & 127, by = lin >> 7;
    const int brow = bx * 128;

    const bf16* A;
    const bf16* Bt;
    if (MODE == 0) {
        A = P.hM0;
        Bt = bz ? P.WtY : P.WtM;
    } else {
        A = bz ? ((t & 1) ? P.hY1 : P.hY0) : ((t & 1) ? P.hM1 : P.hM0);
        Bt = bz ? P.UtY : P.UtM;
    }

    const int fr = lane & 15, fq = lane >> 4;
    const int wr = wave >> 1, wc = wave & 1;

    const uint64_t abase =
        (uint64_t)(const char*)A + (uint64_t)(bx * 8 + wr * 4) * 16384 + lane * 16;
    const uint64_t bbase =
        (uint64_t)(const char*)Bt + (uint64_t)(by * 8 + wc * 4) * 16384 + lane * 16;

    f32x4 acc[4][4];
#pragma unroll
    for (int m = 0; m < 4; ++m)
#pragma unroll
        for (int n = 0; n < 4; ++n) acc[m][n] = (f32x4){0.f, 0.f, 0.f, 0.f};

    i32x4 afr[2][4], bfr[2][4];

#define AGLOAD(bank, kts)                                                         \
    do {                                                                          \
        uint64_t _a = abase + (uint64_t)(kts) * 1024;                             \
        asm volatile("global_load_dwordx4 %0, %1, off"                            \
                     : "=&v"(afr[bank][0]) : "v"(_a) : "memory");                 \
        asm volatile("global_load_dwordx4 %0, %1, off"                            \
                     : "=&v"(afr[bank][1]) : "v"(_a + 16384) : "memory");         \
        asm volatile("global_load_dwordx4 %0, %1, off"                            \
                     : "=&v"(afr[bank][2]) : "v"(_a + 32768) : "memory");         \
        asm volatile("global_load_dwordx4 %0, %1, off"                            \
                     : "=&v"(afr[bank][3]) : "v"(_a + 49152) : "memory");         \
    } while (0)
#define BGLOAD(bank, kts)                                                         \
    do {                                                                          \
        uint64_t _b = bbase + (uint64_t)(kts) * 1024;                             \
        asm volatile("global_load_dwordx4 %0, %1, off"                            \
                     : "=&v"(bfr[bank][0]) : "v"(_b) : "memory");                 \
        asm volatile("global_load_dwordx4 %0, %1, off"                            \
                     : "=&v"(bfr[bank][1]) : "v"(_b + 16384) : "memory");         \
        asm volatile("global_load_dwordx4 %0, %1, off"                            \
                     : "=&v"(bfr[bank][2]) : "v"(_b + 32768) : "memory");         \
        asm volatile("global_load_dwordx4 %0, %1, off"                            \
                     : "=&v"(bfr[bank][3]) : "v"(_b + 49152) : "memory");         \
    } while (0)

    AGLOAD(0, 0);
    BGLOAD(0, 0);
    AGLOAD(1, 1);
    BGLOAD(1, 1);

#pragma unroll
    for (int kt = 0; kt < NT; ++kt) {
        if (kt < NT - 1) {
            WAIT_VM(8);
        } else {
            WAIT_VM(0);
        }
        __builtin_amdgcn_s_setprio(1);
#pragma unroll
        for (int m = 0; m < 4; ++m)
#pragma unroll
            for (int n = 0; n < 4; ++n)
                acc[m][n] = MFMA16(__builtin_bit_cast(bf16x8, afr[kt & 1][m]),
                                   __builtin_bit_cast(bf16x8, bfr[kt & 1][n]), acc[m][n]);
        __builtin_amdgcn_s_setprio(0);
        __builtin_amdgcn_sched_barrier(0);
        if (kt + 2 < NT) {
            AGLOAD(kt & 1, kt + 2);
            BGLOAD(kt & 1, kt + 2);
        }
    }
#undef AGLOAD
#undef BGLOAD

    const int jb = by * 2 + wc;     // 0..31
    const int hcol = jb * 16 + fr;  // 0..511
    const int rowbase = brow + wr * 64 + fq * 4;
    const int rb0 = (rowbase >> 2);

    if (MODE == 0) {
        const float* bias = bz ? P.by_ : P.bm;
        bf16* XO = bz ? P.xwY : P.xwM;
        float b0 = bias[hcol], b1 = bias[512 + hcol], b2 = bias[1024 + hcol],
              b3 = bias[1536 + hcol];
#pragma unroll
        for (int m = 0; m < 4; ++m) {
            bf16x8 v0, v1;
#pragma unroll
            for (int j = 0; j < 2; ++j) {
                v0[j * 4 + 0] = (bf16)(acc[m][0][j] + b0);
                v0[j * 4 + 1] = (bf16)(acc[m][1][j] + b1);
                v0[j * 4 + 2] = (bf16)(acc[m][2][j] + b2);
                v0[j * 4 + 3] = (bf16)(acc[m][3][j] + b3);
            }
#pragma unroll
            for (int j = 2; j < 4; ++j) {
                v1[(j - 2) * 4 + 0] = (bf16)(acc[m][0][j] + b0);
                v1[(j - 2) * 4 + 1] = (bf16)(acc[m][1][j] + b1);
                v1[(j - 2) * 4 + 2] = (bf16)(acc[m][2][j] + b2);
                v1[(j - 2) * 4 + 3] = (bf16)(acc[m][3][j] + b3);
            }
            bf16* o = XO + ((size_t)(rb0 + m * 4) * 512 + hcol) * 16;
            *(bf16x8*)(o) = v0;
            *(bf16x8*)(o + 8) = v1;
        }
    } else {
        float* Cb = bz ? P.cY : P.cM;
        bf16* Ho = bz ? (((t + 1) & 1) ? P.hY1 : P.hY0)
                      : (((t + 1) & 1) ? P.hM1 : P.hM0);
        const bf16* xw = bz ? P.xwY : P.xwM;
        const float* Wc2 = bz ? P.Wc2Y : P.Wc2M;
        f32x4 wcv0 = *(const f32x4*)(Wc2 + hcol * 12);
        f32x4 wcv1 = *(const f32x4*)(Wc2 + hcol * 12 + 4);
        f32x4 wcv2 = *(const f32x4*)(Wc2 + hcol * 12 + 8);
        const int ktc = jb >> 1;
        const int fqp = (jb & 1) * 2 + (fr >> 3);
        bf16* hob = Ho + (((size_t)((brow >> 4) + wr * 4) * 16 + ktc) * 64 + fqp * 16 +
                          fq * 4) * 8 + (fr & 7);
#pragma unroll
        for (int m = 0; m < 4; ++m) {
            const size_t co = ((size_t)(rb0 + m * 4) * 512 + hcol);
            const bf16* xp = xw + co * 16;
            bf16x8 xv0 = *(const bf16x8*)(xp);
            bf16x8 xv1 = *(const bf16x8*)(xp + 8);
            f32x4 cvm = *(const f32x4*)(Cb + co * 4);
            const int row0 = rowbase + m * 16;
            f32x4 cd[4];
#pragma unroll
            for (int j = 0; j < 4; ++j)
                cd[j] = *(const f32x4*)(P.condT4 + ((size_t)t * B_TOT + row0 + j) * 4);
            f32x4 cnew;
            bf16* hom = hob + (size_t)m * 16 * 64 * 8;
#pragma unroll
            for (int j = 0; j < 4; ++j) {
                float z[4];
#pragma unroll
                for (int g = 0; g < 4; ++g) {
                    float xwv = (j < 2) ? (float)xv0[j * 4 + g] : (float)xv1[(j - 2) * 4 + g];
                    z[g] = acc[m][g][j] + xwv + cd[j][0] * wcv0[g] + cd[j][1] * wcv1[g] +
                           cd[j][2] * wcv2[g];
                }
                float ii = fsigm(z[0]);
                float ff = fsigm(z[1]);
                float gg = ftanh(z[2]);
                float oo = fsigm(z[3]);
                float cn = ff * cvm[j] + ii * gg;
                cnew[j] = cn;
                hom[j * 8] = (bf16)(oo * ftanh(cn));
            }
            *(f32x4*)(Cb + co * 4) = cnew;
        }
    }
}

// heads item: 64 rows (4 waves x 16 rows), step th; reads h[(th+1)&1].
__device__ __forceinline__ void heads_item(const DecP& P, float* zbuf, int hb, int th) {
    const int tid = threadIdx.x, wave = tid >> 6, lane = tid & 63;
    const int fr = lane & 15, fq = lane >> 4;
    const int rbase = hb * 64 + wave * 16;
    const int rg = rbase >> 4;
    const int a = (th + 1) & 1;
    const bf16* hm = a ? P.hM1 : P.hM0;
    const bf16* hy = a ? P.hY1 : P.hY0;

    f32x4 am0 = {0.f, 0.f, 0.f, 0.f}, am1 = {0.f, 0.f, 0.f, 0.f}, ay0 = {0.f, 0.f, 0.f, 0.f};

    for (int kt = 0; kt < 16; ++kt) {
        const size_t ao = ((size_t)(rg * 16 + kt) * 64 + lane) * 8;
        bf16x8 a0 = *(const bf16x8*)(hm + ao);
        bf16x8 y0 = *(const bf16x8*)(hy + ao);
        const int k0 = kt * 32;
        const size_t bo = (size_t)fr * DH + k0 + fq * 8;
        bf16x8 b0 = *(const bf16x8*)(P.WhmT + bo);
        bf16x8 b1 = *(const bf16x8*)(P.WhmT + bo + 16 * DH);
        bf16x8 yb = *(const bf16x8*)(P.WhyT + bo);
        am0 = MFMA16(a0, b0, am0);
        am1 = MFMA16(a0, b1, am1);
        ay0 = MFMA16(y0, yb, ay0);
    }

    float* zm = zbuf + wave * 768;  // [16][32]
    float* zy = zm + 512;           // [16][16]
#pragma unroll
    for (int j = 0; j < 4; ++j) {
        int rl = fq * 4 + j;
        zm[rl * 32 + fr] = am0[j] + P.tscm[th * 32 + fr];
        zm[rl * 32 + 16 + fr] = am1[j] + P.tscm[th * 32 + 16 + fr];
        zy[rl * 16 + fr] = ay0[j] + P.tscy[th * 16 + fr];
    }
    __syncthreads();

    const int r = lane & 15;
    const size_t grow = (size_t)rbase + r;
    if (lane < 16) {
        float z[30];
#pragma unroll
        for (int i = 0; i < 30; ++i) z[i] = zm[r * 32 + i];
        float* o = P.out + (grow * SEQ + th) * 30;
        float mx = z[0];
#pragma unroll
        for (int i = 1; i < 5; ++i) mx = fmaxf(mx, z[i]);
        float e[5], s = 0.f;
#pragma unroll
        for (int i = 0; i < 5; ++i) {
            e[i] = __expf(z[i] - mx);
            s += e[i];
        }
        float inv = __fdividef(1.f, s);
#pragma unroll
        for (int i = 0; i < 5; ++i) o[i] = e[i] * inv;
#pragma unroll
        for (int i = 5; i < 10; ++i) o[i] = z[i];
#pragma unroll
        for (int i = 10; i < 15; ++i) o[i] = __expf(z[i]);
#pragma unroll
        for (int i = 15; i < 20; ++i) o[i] = z[i];
#pragma unroll
        for (int i = 20; i < 25; ++i) o[i] = __expf(z[i]);
#pragma unroll
        for (int i = 25; i < 30; ++i) o[i] = ftanh(z[i]);
    } else if (lane < 32) {
        float z[15];
#pragma unroll
        for (int i = 0; i < 15; ++i) z[i] = zy[r * 16 + i];
        float* o = P.out + (size_t)B_TOT * SEQ * 30 + (grow * SEQ + th) * 15;
        float mx = z[0];
#pragma unroll
        for (int i = 1; i < 5; ++i) mx = fmaxf(mx, z[i]);
        float e[5], s = 0.f;
#pragma unroll
        for (int i = 0; i < 5; ++i) {
            e[i] = __expf(z[i] - mx);
            s += e[i];
        }
        float inv = __fdividef(1.f, s);
#pragma unroll
        for (int i = 0; i < 5; ++i) o[i] = e[i] * inv;
#pragma unroll
        for (int i = 5; i < 10; ++i) o[i] = z[i];
#pragma unroll
        for (int i = 10; i < 15; ++i) o[i] = __expf(z[i]);
    }
    __syncthreads();
}

// One work item. t: -1 = MODE0 xw precompute; 0..SEQ-1 = LSTM step t (+ heads
// of step t-1 on items >= NGEMM); SEQ = heads of final step only.
__device__ __forceinline__ void run_item(const DecP& P, float* zbuf, int item, int t) {
    if (item < NGEMM) {
        if (t < 0)
            gemm_item<0>(P, item, 0);
        else if (t < SEQ)
            gemm_item<1>(P, item, t);
    } else if (item < NITEM) {
        if (t >= 1) heads_item(P, zbuf, item - NGEMM, t - 1);
    }
}

template <bool PERSIST>
__global__ __launch_bounds__(256, 3) void decoder_step(DecP P, int t0, int itemOff) {
    __shared__ float zbuf[4 * 768];  // heads scratch, 12 KiB
    if constexpr (PERSIST) {
        cg::grid_group grid = cg::this_grid();
        const int blk = blockIdx.x;
        for (int t = -1; t <= SEQ; ++t) {
            for (int r = 0; r < 6; ++r) {
                const int it = r * NBLK + blk;
                if (it < NITEM) run_item(P, zbuf, it, t);
            }
            __threadfence();
            grid.sync();
        }
    } else {
        run_item(P, zbuf, blockIdx.x + itemOff, t0);
    }
}

// ---------------------------------------------------------------------------
extern "C" void kernel_launch(void* const* d_in, const int* in_sizes, int n_in,
                              void* d_out, int out_size, void* d_ws, size_t ws_size,
                              hipStream_t stream) {
    const float* cond = (const float*)d_in[0];
    const float* sh = (const float*)d_in[1];
    const float* sc = (const float*)d_in[2];
    const float* Wm = (const float*)d_in[3];
    const float* Um = (const float*)d_in[4];
    const float* bm = (const float*)d_in[5];
    const float* Whm = (const float*)d_in[6];
    const float* bhm = (const float*)d_in[7];
    const float* Wy = (const float*)d_in[8];
    const float* Uy = (const float*)d_in[9];
    const float* by_ = (const float*)d_in[10];
    const float* Why = (const float*)d_in[11];
    const float* bhy = (const float*)d_in[12];
    float* out = (float*)d_out;

    char* p = (char*)d_ws;
    auto take = [&](size_t bytes) {
        char* r = p;
        p += (bytes + 255) & ~(size_t)255;
        return r;
    };
    bf16* UtM = (bf16*)take((size_t)ZW * DH * 2);
    bf16* UtY = (bf16*)take((size_t)ZW * DH * 2);
    bf16* WtM = (bf16*)take((size_t)ZW * DH * 2);
    bf16* WtY = (bf16*)take((size_t)ZW * DH * 2);
    float* Wc2M = (float*)take(512 * 12 * 4);
    float* Wc2Y = (float*)take(512 * 12 * 4);
    bf16* WhmT = (bf16*)take(32 * DH * 2);
    bf16* WhyT = (bf16*)take(16 * DH * 2);
    float* tscm = (float*)take(SEQ * 32 * 4);
    float* tscy = (float*)take(SEQ * 16 * 4);
    float* condT4 = (float*)take((size_t)SEQ * B_TOT * 4 * 4);
    bf16* xwM = (bf16*)take((size_t)B_TOT * ZW * 2);
    bf16* xwY = (bf16*)take((size_t)B_TOT * ZW * 2);
    bf16* hM0 = (bf16*)take((size_t)B_TOT * DH * 2);
    bf16* hM1 = (bf16*)take((size_t)B_TOT * DH * 2);
    bf16* hY0 = (bf16*)take((size_t)B_TOT * DH * 2);
    bf16* hY1 = (bf16*)take((size_t)B_TOT * DH * 2);
    float* cMb = (float*)take((size_t)B_TOT * DH * 4);
    float* cYb = (float*)take((size_t)B_TOT * DH * 4);

    init_state<<<(B_TOT * DH) / 256, 256, 0, stream>>>(sh, hM0, hY0);
    build_c3<<<(B_TOT * DH) / 256, 256, 0, stream>>>(sc, cMb, cYb);
    reorder_weights<<<(4 * ZW * DH) / 256, 256, 0, stream>>>(Um, Uy, Wm, Wy, UtM, UtY, WtM, WtY);
    build_wc2<<<(2 * 512 * 12 + 255) / 256, 256, 0, stream>>>(Wm, Wy, Wc2M, Wc2Y);
    cond_transpose<<<(SEQ * B_TOT + 255) / 256, 256, 0, stream>>>(cond, condT4);
    build_heads<<<(32 * 512 + 16 * 512 + SEQ * 32 + SEQ * 16 + 255) / 256, 256, 0, stream>>>(
        Whm, bhm, Why, bhy, WhmT, WhyT, tscm, tscy);

    DecP P;
    P.hM0 = hM0;
    P.hM1 = hM1;
    P.hY0 = hY0;
    P.hY1 = hY1;
    P.UtM = UtM;
    P.UtY = UtY;
    P.WtM = WtM;
    P.WtY = WtY;
    P.xwM = xwM;
    P.xwY = xwY;
    P.Wc2M = Wc2M;
    P.Wc2Y = Wc2Y;
    P.bm = bm;
    P.by_ = by_;
    P.cM = cMb;
    P.cY = cYb;
    P.condT4 = condT4;
    P.WhmT = WhmT;
    P.WhyT = WhyT;
    P.tscm = tscm;
    P.tscy = tscy;
    P.out = out;

    int zero = 0;
    void* kargs[] = {(void*)&P, (void*)&zero, (void*)&zero};
    hipError_t err = hipLaunchCooperativeKernel(
        reinterpret_cast<void*>(&decoder_step<true>), dim3(NBLK), dim3(256), kargs, 0, stream);
    if (err != hipSuccess) {
        (void)hipGetLastError();  // clear; fall back to per-step launches
        decoder_step<false><<<NGEMM, 256, 0, stream>>>(P, -1, 0);
        for (int t = 0; t < SEQ; ++t)
            decoder_step<false><<<NITEM, 256, 0, stream>>>(P, t, 0);
        decoder_step<false><<<NITEM - NGEMM, 256, 0, stream>>>(P, SEQ, NGEMM);
    }
}

// Round 10
// 6974.711 us; speedup vs baseline: 2.8695x; 2.8695x over previous
//
#include <hip/hip_runtime.h>

typedef __bf16 bf16;
typedef __attribute__((ext_vector_type(8))) __bf16 bf16x8;
typedef __attribute__((ext_vector_type(4))) __bf16 bf16x4;
typedef __attribute__((ext_vector_type(4))) float f32x4;
typedef __attribute__((ext_vector_type(4))) int i32x4;

#define B_TOT 16384
#define SEQ 50
#define DH 512
#define ZW 2048  // 4*DH
#define NT 16    // K-tiles of 32 (K = 512)
#define NGEMM 4096  // 128 bx * 16 by * 2 bz
#define NITEM 4352  // + 256 heads chunks (64 rows each)

#define MFMA16(a, b, c) __builtin_amdgcn_mfma_f32_16x16x32_bf16(a, b, c, 0, 0, 0)

__device__ __forceinline__ float fsigm(float x) {
    return __fdividef(1.0f, 1.0f + __expf(-x));
}
__device__ __forceinline__ float ftanh(float x) {
    float e = __expf(2.0f * x);
    return 1.0f - __fdividef(2.0f, e + 1.0f);
}

// ---------------------------------------------------------------------------
// Fragment layout (both GEMM operands):
//   frag[((rg*16 + kt)*64 + fq*16 + fr)]*8 + e <-> element [rg*16+fr][kt*32+fq*8+e]
// Strides: rg = 16384 B, kt = 1024 B, lane-slot = 16 B.
// ---------------------------------------------------------------------------

__global__ void init_state(const float* __restrict__ sh,
                           bf16* __restrict__ h0m, bf16* __restrict__ h0y) {
    size_t i = (size_t)blockIdx.x * 256 + threadIdx.x;
    int row = i >> 9, k = i & 511;
    size_t off = (((size_t)(row >> 4) * 16 + (k >> 5)) * 64 + ((k >> 3) & 3) * 16 +
                  (row & 15)) * 8 + (k & 7);
    bf16 hb = (bf16)sh[i];
    h0m[off] = hb;
    h0y[off] = hb;
}

// c3[row>>2][hcol][row&3] f32, duplicated into cM and cY.
__global__ void build_c3(const float* __restrict__ src,
                         float* __restrict__ dM, float* __restrict__ dY) {
    size_t i = (size_t)blockIdx.x * 256 + threadIdx.x;
    int row = i >> 9, hcol = i & 511;
    float v = src[i];
    size_t o = ((size_t)(row >> 2) * 512 + hcol) * 4 + (row & 3);
    dM[o] = v;
    dY[o] = v;
}

__device__ __forceinline__ int orig_col(int colp) {
    return ((colp >> 4) & 3) * 512 + ((colp >> 6) << 4) + (colp & 15);
}

// B-operands (U^T, W^T) in fragment layout.
__global__ void reorder_weights(const float* __restrict__ Um, const float* __restrict__ Uy,
                                const float* __restrict__ Wm, const float* __restrict__ Wy,
                                bf16* __restrict__ UtM, bf16* __restrict__ UtY,
                                bf16* __restrict__ WtM, bf16* __restrict__ WtY) {
    int idx = blockIdx.x * 256 + threadIdx.x;
    int which = idx >> 20;
    int r = idx & ((1 << 20) - 1);
    int colp = r >> 9, k = r & 511;
    int orig = orig_col(colp);
    const float* src = which == 0 ? Um : which == 1 ? Uy : which == 2 ? Wm : Wy;
    bf16* dst = which == 0 ? UtM : which == 1 ? UtY : which == 2 ? WtM : WtY;
    int cb = colp >> 4, fr = colp & 15;
    int kt = k >> 5, fq = (k >> 3) & 3, e = k & 7;
    int lane = fq * 16 + fr;
    dst[(((size_t)(cb * 16 + kt) * 64 + lane) << 3) + e] = (bf16)src[(size_t)k * ZW + orig];
}

// Wc2[hcol][r(3)][g(4)] f32
__global__ void build_wc2(const float* __restrict__ Wm, const float* __restrict__ Wy,
                          float* __restrict__ Wc2M, float* __restrict__ Wc2Y) {
    int idx = blockIdx.x * 256 + threadIdx.x;
    if (idx >= 2 * 512 * 12) return;
    int which = idx / 6144;
    int r2 = idx % 6144;
    int hcol = r2 / 12, rg = r2 % 12;
    int r = rg >> 2, g = rg & 3;
    const float* src = which ? Wy : Wm;
    float* dst = which ? Wc2Y : Wc2M;
    dst[hcol * 12 + rg] = src[(size_t)(512 + r) * ZW + g * 512 + hcol];
}

// condT4[t][row][4] f32
__global__ void cond_transpose(const float* __restrict__ cond, float* __restrict__ condT4) {
    int idx = blockIdx.x * 256 + threadIdx.x;
    if (idx >= SEQ * B_TOT) return;
    int t = idx / B_TOT, row = idx % B_TOT;
    const float* s = cond + ((size_t)row * SEQ + t) * 3;
    f32x4 v = {s[0], s[1], s[2], 0.f};
    *(f32x4*)(condT4 + (size_t)idx * 4) = v;
}

__global__ void build_heads(const float* __restrict__ Whm, const float* __restrict__ bhm,
                            const float* __restrict__ Why, const float* __restrict__ bhy,
                            bf16* __restrict__ WhmT, bf16* __restrict__ WhyT,
                            float* __restrict__ tscm, float* __restrict__ tscy) {
    int i = blockIdx.x * 256 + threadIdx.x;
    const int N1 = 32 * 512, N2 = 16 * 512, N3 = SEQ * 32, N4 = SEQ * 16;
    if (i < N1) {
        int n = i >> 9, k = i & 511;
        WhmT[i] = (bf16)(n < 30 ? Whm[k * 30 + n] : 0.f);
    } else if (i < N1 + N2) {
        int j = i - N1;
        int n = j >> 9, k = j & 511;
        WhyT[j] = (bf16)(n < 15 ? Why[k * 15 + n] : 0.f);
    } else if (i < N1 + N2 + N3) {
        int j = i - (N1 + N2);
        int tt = j >> 5, col = j & 31;
        float v = 0.f;
        if (col < 30) {
            v = bhm[col];
            for (int s = 0; s <= tt; ++s) v += Whm[(512 + s) * 30 + col];
        }
        tscm[j] = v;
    } else if (i < N1 + N2 + N3 + N4) {
        int j = i - (N1 + N2 + N3);
        int tt = j >> 4, col = j & 15;
        float v = 0.f;
        if (col < 15) {
            v = bhy[col];
            for (int s = 0; s <= tt; ++s) v += Why[(512 + s) * 15 + col];
        }
        tscy[j] = v;
    }
}

// ---------------------------------------------------------------------------
// Decoder work items.
// ---------------------------------------------------------------------------

struct DecP {
    bf16 *hM0, *hM1, *hY0, *hY1;
    const bf16 *UtM, *UtY, *WtM, *WtY;
    bf16 *xwM, *xwY;
    const float *Wc2M, *Wc2Y, *bm, *by_;
    float *cM, *cY;
    const float* condT4;
    const bf16 *WhmT, *WhyT;
    const float *tscm, *tscy;
    float* out;
};

#define WAIT_VM(n)                                                  \
    do {                                                            \
        asm volatile("s_waitcnt vmcnt(" #n ")" ::: "memory");       \
        __builtin_amdgcn_sched_barrier(0);                          \
    } while (0)

// gemm item: 128x128 tile, BK=32, 4 waves (2x2), no LDS, no barriers.
// DEPTH-4 register pipeline: 4 fragment banks, 32 loads in flight,
// steady-state vmcnt(24) -> ~3 iterations of latency cover.
template <int MODE>
__device__ __forceinline__ void gemm_item(const DecP& P, int item, int t) {
    const int tid = threadIdx.x;
    const int wave = tid >> 6, lane = tid & 63;
    const int bz = item >> 11;
    // XCD-aware swizzle: each XCD owns a 16-wide bx band, by iterates within.
    const int lin = item & 2047;
    const int xcd = lin & 7, jj2 = lin >> 3;
    const int bx = xcd * 16 + (jj2 >> 4);
    const int by = jj2 & 15;
    const int brow = bx * 128;

    const bf16* A;
    const bf16* Bt;
    if (MODE == 0) {
        A = P.hM0;
        Bt = bz ? P.WtY : P.WtM;
    } else {
        A = bz ? ((t & 1) ? P.hY1 : P.hY0) : ((t & 1) ? P.hM1 : P.hM0);
        Bt = bz ? P.UtY : P.UtM;
    }

    const int fr = lane & 15, fq = lane >> 4;
    const int wr = wave >> 1, wc = wave & 1;

    const uint64_t abase =
        (uint64_t)(const char*)A + (uint64_t)(bx * 8 + wr * 4) * 16384 + lane * 16;
    const uint64_t bbase =
        (uint64_t)(const char*)Bt + (uint64_t)(by * 8 + wc * 4) * 16384 + lane * 16;

    f32x4 acc[4][4];
#pragma unroll
    for (int m = 0; m < 4; ++m)
#pragma unroll
        for (int n = 0; n < 4; ++n) acc[m][n] = (f32x4){0.f, 0.f, 0.f, 0.f};

    i32x4 afr[4][4], bfr[4][4];

#define AGLOAD(bank, kts)                                                         \
    do {                                                                          \
        uint64_t _a = abase + (uint64_t)(kts) * 1024;                             \
        asm volatile("global_load_dwordx4 %0, %1, off"                            \
                     : "=&v"(afr[bank][0]) : "v"(_a) : "memory");                 \
        asm volatile("global_load_dwordx4 %0, %1, off"                            \
                     : "=&v"(afr[bank][1]) : "v"(_a + 16384) : "memory");         \
        asm volatile("global_load_dwordx4 %0, %1, off"                            \
                     : "=&v"(afr[bank][2]) : "v"(_a + 32768) : "memory");         \
        asm volatile("global_load_dwordx4 %0, %1, off"                            \
                     : "=&v"(afr[bank][3]) : "v"(_a + 49152) : "memory");         \
    } while (0)
#define BGLOAD(bank, kts)                                                         \
    do {                                                                          \
        uint64_t _b = bbase + (uint64_t)(kts) * 1024;                             \
        asm volatile("global_load_dwordx4 %0, %1, off"                            \
                     : "=&v"(bfr[bank][0]) : "v"(_b) : "memory");                 \
        asm volatile("global_load_dwordx4 %0, %1, off"                            \
                     : "=&v"(bfr[bank][1]) : "v"(_b + 16384) : "memory");         \
        asm volatile("global_load_dwordx4 %0, %1, off"                            \
                     : "=&v"(bfr[bank][2]) : "v"(_b + 32768) : "memory");         \
        asm volatile("global_load_dwordx4 %0, %1, off"                            \
                     : "=&v"(bfr[bank][3]) : "v"(_b + 49152) : "memory");         \
    } while (0)

    // prologue: tiles 0..3 in flight (32 loads)
    AGLOAD(0, 0);
    BGLOAD(0, 0);
    AGLOAD(1, 1);
    BGLOAD(1, 1);
    AGLOAD(2, 2);
    BGLOAD(2, 2);
    AGLOAD(3, 3);
    BGLOAD(3, 3);

#pragma unroll
    for (int kt = 0; kt < NT; ++kt) {
        // retire tile kt; keep tiles kt+1..kt+3 (as available) in flight
        if (kt < NT - 3) {
            WAIT_VM(24);
        } else if (kt == NT - 3) {
            WAIT_VM(16);
        } else if (kt == NT - 2) {
            WAIT_VM(8);
        } else {
            WAIT_VM(0);
        }
        __builtin_amdgcn_s_setprio(1);
#pragma unroll
        for (int m = 0; m < 4; ++m)
#pragma unroll
            for (int n = 0; n < 4; ++n)
                acc[m][n] = MFMA16(__builtin_bit_cast(bf16x8, afr[kt & 3][m]),
                                   __builtin_bit_cast(bf16x8, bfr[kt & 3][n]), acc[m][n]);
        __builtin_amdgcn_s_setprio(0);
        __builtin_amdgcn_sched_barrier(0);
        if (kt + 4 < NT) {
            AGLOAD(kt & 3, kt + 4);
            BGLOAD(kt & 3, kt + 4);
        }
    }
#undef AGLOAD
#undef BGLOAD

    const int jb = by * 2 + wc;     // 0..31
    const int hcol = jb * 16 + fr;  // 0..511
    const int rowbase = brow + wr * 64 + fq * 4;
    const int rb0 = (rowbase >> 2);

    if (MODE == 0) {
        const float* bias = bz ? P.by_ : P.bm;
        bf16* XO = bz ? P.xwY : P.xwM;
        float b0 = bias[hcol], b1 = bias[512 + hcol], b2 = bias[1024 + hcol],
              b3 = bias[1536 + hcol];
#pragma unroll
        for (int m = 0; m < 4; ++m) {
            bf16x8 v0, v1;
#pragma unroll
            for (int j = 0; j < 2; ++j) {
                v0[j * 4 + 0] = (bf16)(acc[m][0][j] + b0);
                v0[j * 4 + 1] = (bf16)(acc[m][1][j] + b1);
                v0[j * 4 + 2] = (bf16)(acc[m][2][j] + b2);
                v0[j * 4 + 3] = (bf16)(acc[m][3][j] + b3);
            }
#pragma unroll
            for (int j = 2; j < 4; ++j) {
                v1[(j - 2) * 4 + 0] = (bf16)(acc[m][0][j] + b0);
                v1[(j - 2) * 4 + 1] = (bf16)(acc[m][1][j] + b1);
                v1[(j - 2) * 4 + 2] = (bf16)(acc[m][2][j] + b2);
                v1[(j - 2) * 4 + 3] = (bf16)(acc[m][3][j] + b3);
            }
            bf16* o = XO + ((size_t)(rb0 + m * 4) * 512 + hcol) * 16;
            *(bf16x8*)(o) = v0;
            *(bf16x8*)(o + 8) = v1;
        }
    } else {
        float* Cb = bz ? P.cY : P.cM;
        bf16* Ho = bz ? (((t + 1) & 1) ? P.hY1 : P.hY0)
                      : (((t + 1) & 1) ? P.hM1 : P.hM0);
        const bf16* xw = bz ? P.xwY : P.xwM;
        const float* Wc2 = bz ? P.Wc2Y : P.Wc2M;
        f32x4 wcv0 = *(const f32x4*)(Wc2 + hcol * 12);
        f32x4 wcv1 = *(const f32x4*)(Wc2 + hcol * 12 + 4);
        f32x4 wcv2 = *(const f32x4*)(Wc2 + hcol * 12 + 8);
        const int ktc = jb >> 1;
        const int fqp = (jb & 1) * 2 + (fr >> 3);
        bf16* hob = Ho + (((size_t)((brow >> 4) + wr * 4) * 16 + ktc) * 64 + fqp * 16 +
                          fq * 4) * 8 + (fr & 7);
#pragma unroll
        for (int m = 0; m < 4; ++m) {
            const size_t co = ((size_t)(rb0 + m * 4) * 512 + hcol);
            const bf16* xp = xw + co * 16;
            bf16x8 xv0 = *(const bf16x8*)(xp);
            bf16x8 xv1 = *(const bf16x8*)(xp + 8);
            f32x4 cvm = *(const f32x4*)(Cb + co * 4);
            const int row0 = rowbase + m * 16;
            f32x4 cd[4];
#pragma unroll
            for (int j = 0; j < 4; ++j)
                cd[j] = *(const f32x4*)(P.condT4 + ((size_t)t * B_TOT + row0 + j) * 4);
            f32x4 cnew;
            bf16* hom = hob + (size_t)m * 16 * 64 * 8;
#pragma unroll
            for (int j = 0; j < 4; ++j) {
                float z[4];
#pragma unroll
                for (int g = 0; g < 4; ++g) {
                    float xwv = (j < 2) ? (float)xv0[j * 4 + g] : (float)xv1[(j - 2) * 4 + g];
                    z[g] = acc[m][g][j] + xwv + cd[j][0] * wcv0[g] + cd[j][1] * wcv1[g] +
                           cd[j][2] * wcv2[g];
                }
                float ii = fsigm(z[0]);
                float ff = fsigm(z[1]);
                float gg = ftanh(z[2]);
                float oo = fsigm(z[3]);
                float cn = ff * cvm[j] + ii * gg;
                cnew[j] = cn;
                hom[j * 8] = (bf16)(oo * ftanh(cn));
            }
            *(f32x4*)(Cb + co * 4) = cnew;
        }
    }
}

// heads item: 64 rows (4 waves x 16 rows), step th; reads h[(th+1)&1].
__device__ __forceinline__ void heads_item(const DecP& P, float* zbuf, int hb, int th) {
    const int tid = threadIdx.x, wave = tid >> 6, lane = tid & 63;
    const int fr = lane & 15, fq = lane >> 4;
    const int rbase = hb * 64 + wave * 16;
    const int rg = rbase >> 4;
    const int a = (th + 1) & 1;
    const bf16* hm = a ? P.hM1 : P.hM0;
    const bf16* hy = a ? P.hY1 : P.hY0;

    f32x4 am0 = {0.f, 0.f, 0.f, 0.f}, am1 = {0.f, 0.f, 0.f, 0.f}, ay0 = {0.f, 0.f, 0.f, 0.f};

    for (int kt = 0; kt < 16; ++kt) {
        const size_t ao = ((size_t)(rg * 16 + kt) * 64 + lane) * 8;
        bf16x8 a0 = *(const bf16x8*)(hm + ao);
        bf16x8 y0 = *(const bf16x8*)(hy + ao);
        const int k0 = kt * 32;
        const size_t bo = (size_t)fr * DH + k0 + fq * 8;
        bf16x8 b0 = *(const bf16x8*)(P.WhmT + bo);
        bf16x8 b1 = *(const bf16x8*)(P.WhmT + bo + 16 * DH);
        bf16x8 yb = *(const bf16x8*)(P.WhyT + bo);
        am0 = MFMA16(a0, b0, am0);
        am1 = MFMA16(a0, b1, am1);
        ay0 = MFMA16(y0, yb, ay0);
    }

    float* zm = zbuf + wave * 768;  // [16][32]
    float* zy = zm + 512;           // [16][16]
#pragma unroll
    for (int j = 0; j < 4; ++j) {
        int rl = fq * 4 + j;
        zm[rl * 32 + fr] = am0[j] + P.tscm[th * 32 + fr];
        zm[rl * 32 + 16 + fr] = am1[j] + P.tscm[th * 32 + 16 + fr];
        zy[rl * 16 + fr] = ay0[j] + P.tscy[th * 16 + fr];
    }
    __syncthreads();

    const int r = lane & 15;
    const size_t grow = (size_t)rbase + r;
    if (lane < 16) {
        float z[30];
#pragma unroll
        for (int i = 0; i < 30; ++i) z[i] = zm[r * 32 + i];
        float* o = P.out + (grow * SEQ + th) * 30;
        float mx = z[0];
#pragma unroll
        for (int i = 1; i < 5; ++i) mx = fmaxf(mx, z[i]);
        float e[5], s = 0.f;
#pragma unroll
        for (int i = 0; i < 5; ++i) {
            e[i] = __expf(z[i] - mx);
            s += e[i];
        }
        float inv = __fdividef(1.f, s);
#pragma unroll
        for (int i = 0; i < 5; ++i) o[i] = e[i] * inv;
#pragma unroll
        for (int i = 5; i < 10; ++i) o[i] = z[i];
#pragma unroll
        for (int i = 10; i < 15; ++i) o[i] = __expf(z[i]);
#pragma unroll
        for (int i = 15; i < 20; ++i) o[i] = z[i];
#pragma unroll
        for (int i = 20; i < 25; ++i) o[i] = __expf(z[i]);
#pragma unroll
        for (int i = 25; i < 30; ++i) o[i] = ftanh(z[i]);
    } else if (lane < 32) {
        float z[15];
#pragma unroll
        for (int i = 0; i < 15; ++i) z[i] = zy[r * 16 + i];
        float* o = P.out + (size_t)B_TOT * SEQ * 30 + (grow * SEQ + th) * 15;
        float mx = z[0];
#pragma unroll
        for (int i = 1; i < 5; ++i) mx = fmaxf(mx, z[i]);
        float e[5], s = 0.f;
#pragma unroll
        for (int i = 0; i < 5; ++i) {
            e[i] = __expf(z[i] - mx);
            s += e[i];
        }
        float inv = __fdividef(1.f, s);
#pragma unroll
        for (int i = 0; i < 5; ++i) o[i] = e[i] * inv;
#pragma unroll
        for (int i = 5; i < 10; ++i) o[i] = z[i];
#pragma unroll
        for (int i = 10; i < 15; ++i) o[i] = __expf(z[i]);
    }
}

// One dispatch-step kernel. t: -1 = MODE0 xw precompute (grid NGEMM);
// 0..SEQ-1 = LSTM step t + ride-along heads of step t-1 (grid NITEM);
// SEQ = heads of final step only (grid NITEM-NGEMM, itemOff=NGEMM).
__global__ __launch_bounds__(256, 2) void step_kernel(DecP P, int t, int itemOff) {
    __shared__ float zbuf[4 * 768];  // heads scratch, 12 KiB
    const int item = blockIdx.x + itemOff;
    if (item < NGEMM) {
        if (t < 0)
            gemm_item<0>(P, item, 0);
        else if (t < SEQ)
            gemm_item<1>(P, item, t);
    } else if (item < NITEM) {
        if (t >= 1) heads_item(P, zbuf, item - NGEMM, t - 1);
    }
}

// ---------------------------------------------------------------------------
extern "C" void kernel_launch(void* const* d_in, const int* in_sizes, int n_in,
                              void* d_out, int out_size, void* d_ws, size_t ws_size,
                              hipStream_t stream) {
    const float* cond = (const float*)d_in[0];
    const float* sh = (const float*)d_in[1];
    const float* sc = (const float*)d_in[2];
    const float* Wm = (const float*)d_in[3];
    const float* Um = (const float*)d_in[4];
    const float* bm = (const float*)d_in[5];
    const float* Whm = (const float*)d_in[6];
    const float* bhm = (const float*)d_in[7];
    const float* Wy = (const float*)d_in[8];
    const float* Uy = (const float*)d_in[9];
    const float* by_ = (const float*)d_in[10];
    const float* Why = (const float*)d_in[11];
    const float* bhy = (const float*)d_in[12];
    float* out = (float*)d_out;

    char* p = (char*)d_ws;
    auto take = [&](size_t bytes) {
        char* r = p;
        p += (bytes + 255) & ~(size_t)255;
        return r;
    };
    bf16* UtM = (bf16*)take((size_t)ZW * DH * 2);
    bf16* UtY = (bf16*)take((size_t)ZW * DH * 2);
    bf16* WtM = (bf16*)take((size_t)ZW * DH * 2);
    bf16* WtY = (bf16*)take((size_t)ZW * DH * 2);
    float* Wc2M = (float*)take(512 * 12 * 4);
    float* Wc2Y = (float*)take(512 * 12 * 4);
    bf16* WhmT = (bf16*)take(32 * DH * 2);
    bf16* WhyT = (bf16*)take(16 * DH * 2);
    float* tscm = (float*)take(SEQ * 32 * 4);
    float* tscy = (float*)take(SEQ * 16 * 4);
    float* condT4 = (float*)take((size_t)SEQ * B_TOT * 4 * 4);
    bf16* xwM = (bf16*)take((size_t)B_TOT * ZW * 2);
    bf16* xwY = (bf16*)take((size_t)B_TOT * ZW * 2);
    bf16* hM0 = (bf16*)take((size_t)B_TOT * DH * 2);
    bf16* hM1 = (bf16*)take((size_t)B_TOT * DH * 2);
    bf16* hY0 = (bf16*)take((size_t)B_TOT * DH * 2);
    bf16* hY1 = (bf16*)take((size_t)B_TOT * DH * 2);
    float* cMb = (float*)take((size_t)B_TOT * DH * 4);
    float* cYb = (float*)take((size_t)B_TOT * DH * 4);

    init_state<<<(B_TOT * DH) / 256, 256, 0, stream>>>(sh, hM0, hY0);
    build_c3<<<(B_TOT * DH) / 256, 256, 0, stream>>>(sc, cMb, cYb);
    reorder_weights<<<(4 * ZW * DH) / 256, 256, 0, stream>>>(Um, Uy, Wm, Wy, UtM, UtY, WtM, WtY);
    build_wc2<<<(2 * 512 * 12 + 255) / 256, 256, 0, stream>>>(Wm, Wy, Wc2M, Wc2Y);
    cond_transpose<<<(SEQ * B_TOT + 255) / 256, 256, 0, stream>>>(cond, condT4);
    build_heads<<<(32 * 512 + 16 * 512 + SEQ * 32 + SEQ * 16 + 255) / 256, 256, 0, stream>>>(
        Whm, bhm, Why, bhy, WhmT, WhyT, tscm, tscy);

    DecP P;
    P.hM0 = hM0;
    P.hM1 = hM1;
    P.hY0 = hY0;
    P.hY1 = hY1;
    P.UtM = UtM;
    P.UtY = UtY;
    P.WtM = WtM;
    P.WtY = WtY;
    P.xwM = xwM;
    P.xwY = xwY;
    P.Wc2M = Wc2M;
    P.Wc2Y = Wc2Y;
    P.bm = bm;
    P.by_ = by_;
    P.cM = cMb;
    P.cY = cYb;
    P.condT4 = condT4;
    P.WhmT = WhmT;
    P.WhyT = WhyT;
    P.tscm = tscm;
    P.tscy = tscy;
    P.out = out;

    step_kernel<<<NGEMM, 256, 0, stream>>>(P, -1, 0);
    for (int t = 0; t < SEQ; ++t)
        step_kernel<<<NITEM, 256, 0, stream>>>(P, t, 0);
    step_kernel<<<NITEM - NGEMM, 256, 0, stream>>>(P, SEQ, NGEMM);
}

// Round 11
// 6801.476 us; speedup vs baseline: 2.9426x; 1.0255x over previous
//
#include <hip/hip_runtime.h>

typedef __bf16 bf16;
typedef __attribute__((ext_vector_type(8))) __bf16 bf16x8;
typedef __attribute__((ext_vector_type(4))) __bf16 bf16x4;
typedef __attribute__((ext_vector_type(4))) float f32x4;
typedef __attribute__((ext_vector_type(4))) int i32x4;

#define B_TOT 16384
#define SEQ 50
#define DH 512
#define ZW 2048  // 4*DH
#define NT 16    // K-tiles of 32 (K = 512)

// Batch chunking: rows are independent; 8192-row chunks keep the per-chunk
// working set (xw 64MB + c 67MB + h 32MB + U 8MB ~= 171MB) resident in the
// 256MB Infinity Cache across all 50 steps of the chunk.
#define NCHUNK 2
#define CROWS 8192
#define NG0 4096  // MODE0 items: 128 bx * 16 by * 2 bz (full batch)
#define NG1 2048  // MODE1 items: 64 bx * 16 by * 2 bz (one chunk)
#define NH1 128   // heads items per chunk (64 rows each)

#define MFMA16(a, b, c) __builtin_amdgcn_mfma_f32_16x16x32_bf16(a, b, c, 0, 0, 0)

__device__ __forceinline__ float fsigm(float x) {
    return __fdividef(1.0f, 1.0f + __expf(-x));
}
__device__ __forceinline__ float ftanh(float x) {
    float e = __expf(2.0f * x);
    return 1.0f - __fdividef(2.0f, e + 1.0f);
}

// ---------------------------------------------------------------------------
// Fragment layout (both GEMM operands):
//   frag[((rg*16 + kt)*64 + fq*16 + fr)]*8 + e <-> element [rg*16+fr][kt*32+fq*8+e]
// Strides: rg = 16384 B, kt = 1024 B, lane-slot = 16 B.
// ---------------------------------------------------------------------------

__global__ void init_state(const float* __restrict__ sh,
                           bf16* __restrict__ h0m, bf16* __restrict__ h0y) {
    size_t i = (size_t)blockIdx.x * 256 + threadIdx.x;
    int row = i >> 9, k = i & 511;
    size_t off = (((size_t)(row >> 4) * 16 + (k >> 5)) * 64 + ((k >> 3) & 3) * 16 +
                  (row & 15)) * 8 + (k & 7);
    bf16 hb = (bf16)sh[i];
    h0m[off] = hb;
    h0y[off] = hb;
}

// c3[row>>2][hcol][row&3] f32, duplicated into cM and cY.
__global__ void build_c3(const float* __restrict__ src,
                         float* __restrict__ dM, float* __restrict__ dY) {
    size_t i = (size_t)blockIdx.x * 256 + threadIdx.x;
    int row = i >> 9, hcol = i & 511;
    float v = src[i];
    size_t o = ((size_t)(row >> 2) * 512 + hcol) * 4 + (row & 3);
    dM[o] = v;
    dY[o] = v;
}

__device__ __forceinline__ int orig_col(int colp) {
    return ((colp >> 4) & 3) * 512 + ((colp >> 6) << 4) + (colp & 15);
}

// B-operands (U^T, W^T) in fragment layout.
__global__ void reorder_weights(const float* __restrict__ Um, const float* __restrict__ Uy,
                                const float* __restrict__ Wm, const float* __restrict__ Wy,
                                bf16* __restrict__ UtM, bf16* __restrict__ UtY,
                                bf16* __restrict__ WtM, bf16* __restrict__ WtY) {
    int idx = blockIdx.x * 256 + threadIdx.x;
    int which = idx >> 20;
    int r = idx & ((1 << 20) - 1);
    int colp = r >> 9, k = r & 511;
    int orig = orig_col(colp);
    const float* src = which == 0 ? Um : which == 1 ? Uy : which == 2 ? Wm : Wy;
    bf16* dst = which == 0 ? UtM : which == 1 ? UtY : which == 2 ? WtM : WtY;
    int cb = colp >> 4, fr = colp & 15;
    int kt = k >> 5, fq = (k >> 3) & 3, e = k & 7;
    int lane = fq * 16 + fr;
    dst[(((size_t)(cb * 16 + kt) * 64 + lane) << 3) + e] = (bf16)src[(size_t)k * ZW + orig];
}

// Wc2[hcol][r(3)][g(4)] f32
__global__ void build_wc2(const float* __restrict__ Wm, const float* __restrict__ Wy,
                          float* __restrict__ Wc2M, float* __restrict__ Wc2Y) {
    int idx = blockIdx.x * 256 + threadIdx.x;
    if (idx >= 2 * 512 * 12) return;
    int which = idx / 6144;
    int r2 = idx % 6144;
    int hcol = r2 / 12, rg = r2 % 12;
    int r = rg >> 2, g = rg & 3;
    const float* src = which ? Wy : Wm;
    float* dst = which ? Wc2Y : Wc2M;
    dst[hcol * 12 + rg] = src[(size_t)(512 + r) * ZW + g * 512 + hcol];
}

// condT4[t][row][4] f32
__global__ void cond_transpose(const float* __restrict__ cond, float* __restrict__ condT4) {
    int idx = blockIdx.x * 256 + threadIdx.x;
    if (idx >= SEQ * B_TOT) return;
    int t = idx / B_TOT, row = idx % B_TOT;
    const float* s = cond + ((size_t)row * SEQ + t) * 3;
    f32x4 v = {s[0], s[1], s[2], 0.f};
    *(f32x4*)(condT4 + (size_t)idx * 4) = v;
}

__global__ void build_heads(const float* __restrict__ Whm, const float* __restrict__ bhm,
                            const float* __restrict__ Why, const float* __restrict__ bhy,
                            bf16* __restrict__ WhmT, bf16* __restrict__ WhyT,
                            float* __restrict__ tscm, float* __restrict__ tscy) {
    int i = blockIdx.x * 256 + threadIdx.x;
    const int N1 = 32 * 512, N2 = 16 * 512, N3 = SEQ * 32, N4 = SEQ * 16;
    if (i < N1) {
        int n = i >> 9, k = i & 511;
        WhmT[i] = (bf16)(n < 30 ? Whm[k * 30 + n] : 0.f);
    } else if (i < N1 + N2) {
        int j = i - N1;
        int n = j >> 9, k = j & 511;
        WhyT[j] = (bf16)(n < 15 ? Why[k * 15 + n] : 0.f);
    } else if (i < N1 + N2 + N3) {
        int j = i - (N1 + N2);
        int tt = j >> 5, col = j & 31;
        float v = 0.f;
        if (col < 30) {
            v = bhm[col];
            for (int s = 0; s <= tt; ++s) v += Whm[(512 + s) * 30 + col];
        }
        tscm[j] = v;
    } else if (i < N1 + N2 + N3 + N4) {
        int j = i - (N1 + N2 + N3);
        int tt = j >> 4, col = j & 15;
        float v = 0.f;
        if (col < 15) {
            v = bhy[col];
            for (int s = 0; s <= tt; ++s) v += Why[(512 + s) * 15 + col];
        }
        tscy[j] = v;
    }
}

// ---------------------------------------------------------------------------
// Decoder work items.
// ---------------------------------------------------------------------------

struct DecP {
    bf16 *hM0, *hM1, *hY0, *hY1;
    const bf16 *UtM, *UtY, *WtM, *WtY;
    bf16 *xwM, *xwY;
    const float *Wc2M, *Wc2Y, *bm, *by_;
    float *cM, *cY;
    const float* condT4;
    const bf16 *WhmT, *WhyT;
    const float *tscm, *tscy;
    float* out;
};

#define WAIT_VM(n)                                                  \
    do {                                                            \
        asm volatile("s_waitcnt vmcnt(" #n ")" ::: "memory");       \
        __builtin_amdgcn_sched_barrier(0);                          \
    } while (0)

// gemm item: 128x128 tile, BK=32, 4 waves (2x2), no LDS, no barriers.
// Depth-4 register pipeline, counted vmcnt. rowOff selects the batch chunk.
template <int MODE>
__device__ __forceinline__ void gemm_item(const DecP& P, int item, int t, int rowOff) {
    const int tid = threadIdx.x;
    const int wave = tid >> 6, lane = tid & 63;
    // XCD-aware swizzle: each XCD owns a contiguous bx band, by iterates within.
    const int bz = (MODE == 0) ? (item >> 11) : (item >> 10);
    const int lin = (MODE == 0) ? (item & 2047) : (item & 1023);
    const int xcd = lin & 7, jj2 = lin >> 3;
    const int bx = (MODE == 0) ? (xcd * 16 + (jj2 >> 4)) : (xcd * 8 + (jj2 >> 4));
    const int by = jj2 & 15;
    const int brow = rowOff + bx * 128;

    const bf16* A;
    const bf16* Bt;
    if (MODE == 0) {
        A = P.hM0;
        Bt = bz ? P.WtY : P.WtM;
    } else {
        A = bz ? ((t & 1) ? P.hY1 : P.hY0) : ((t & 1) ? P.hM1 : P.hM0);
        Bt = bz ? P.UtY : P.UtM;
    }

    const int fr = lane & 15, fq = lane >> 4;
    const int wr = wave >> 1, wc = wave & 1;

    const uint64_t abase =
        (uint64_t)(const char*)A + (uint64_t)((brow >> 4) + wr * 4) * 16384 + lane * 16;
    const uint64_t bbase =
        (uint64_t)(const char*)Bt + (uint64_t)(by * 8 + wc * 4) * 16384 + lane * 16;

    f32x4 acc[4][4];
#pragma unroll
    for (int m = 0; m < 4; ++m)
#pragma unroll
        for (int n = 0; n < 4; ++n) acc[m][n] = (f32x4){0.f, 0.f, 0.f, 0.f};

    i32x4 afr[4][4], bfr[4][4];

#define AGLOAD(bank, kts)                                                         \
    do {                                                                          \
        uint64_t _a = abase + (uint64_t)(kts) * 1024;                             \
        asm volatile("global_load_dwordx4 %0, %1, off"                            \
                     : "=&v"(afr[bank][0]) : "v"(_a) : "memory");                 \
        asm volatile("global_load_dwordx4 %0, %1, off"                            \
                     : "=&v"(afr[bank][1]) : "v"(_a + 16384) : "memory");         \
        asm volatile("global_load_dwordx4 %0, %1, off"                            \
                     : "=&v"(afr[bank][2]) : "v"(_a + 32768) : "memory");         \
        asm volatile("global_load_dwordx4 %0, %1, off"                            \
                     : "=&v"(afr[bank][3]) : "v"(_a + 49152) : "memory");         \
    } while (0)
#define BGLOAD(bank, kts)                                                         \
    do {                                                                          \
        uint64_t _b = bbase + (uint64_t)(kts) * 1024;                             \
        asm volatile("global_load_dwordx4 %0, %1, off"                            \
                     : "=&v"(bfr[bank][0]) : "v"(_b) : "memory");                 \
        asm volatile("global_load_dwordx4 %0, %1, off"                            \
                     : "=&v"(bfr[bank][1]) : "v"(_b + 16384) : "memory");         \
        asm volatile("global_load_dwordx4 %0, %1, off"                            \
                     : "=&v"(bfr[bank][2]) : "v"(_b + 32768) : "memory");         \
        asm volatile("global_load_dwordx4 %0, %1, off"                            \
                     : "=&v"(bfr[bank][3]) : "v"(_b + 49152) : "memory");         \
    } while (0)

    // prologue: tiles 0..3 in flight (32 loads)
    AGLOAD(0, 0);
    BGLOAD(0, 0);
    AGLOAD(1, 1);
    BGLOAD(1, 1);
    AGLOAD(2, 2);
    BGLOAD(2, 2);
    AGLOAD(3, 3);
    BGLOAD(3, 3);

#pragma unroll
    for (int kt = 0; kt < NT; ++kt) {
        if (kt < NT - 3) {
            WAIT_VM(24);
        } else if (kt == NT - 3) {
            WAIT_VM(16);
        } else if (kt == NT - 2) {
            WAIT_VM(8);
        } else {
            WAIT_VM(0);
        }
        __builtin_amdgcn_s_setprio(1);
#pragma unroll
        for (int m = 0; m < 4; ++m)
#pragma unroll
            for (int n = 0; n < 4; ++n)
                acc[m][n] = MFMA16(__builtin_bit_cast(bf16x8, afr[kt & 3][m]),
                                   __builtin_bit_cast(bf16x8, bfr[kt & 3][n]), acc[m][n]);
        __builtin_amdgcn_s_setprio(0);
        __builtin_amdgcn_sched_barrier(0);
        if (kt + 4 < NT) {
            AGLOAD(kt & 3, kt + 4);
            BGLOAD(kt & 3, kt + 4);
        }
    }
#undef AGLOAD
#undef BGLOAD

    const int jb = by * 2 + wc;     // 0..31
    const int hcol = jb * 16 + fr;  // 0..511
    const int rowbase = brow + wr * 64 + fq * 4;
    const int rb0 = (rowbase >> 2);

    if (MODE == 0) {
        const float* bias = bz ? P.by_ : P.bm;
        bf16* XO = bz ? P.xwY : P.xwM;
        float b0 = bias[hcol], b1 = bias[512 + hcol], b2 = bias[1024 + hcol],
              b3 = bias[1536 + hcol];
#pragma unroll
        for (int m = 0; m < 4; ++m) {
            bf16x8 v0, v1;
#pragma unroll
            for (int j = 0; j < 2; ++j) {
                v0[j * 4 + 0] = (bf16)(acc[m][0][j] + b0);
                v0[j * 4 + 1] = (bf16)(acc[m][1][j] + b1);
                v0[j * 4 + 2] = (bf16)(acc[m][2][j] + b2);
                v0[j * 4 + 3] = (bf16)(acc[m][3][j] + b3);
            }
#pragma unroll
            for (int j = 2; j < 4; ++j) {
                v1[(j - 2) * 4 + 0] = (bf16)(acc[m][0][j] + b0);
                v1[(j - 2) * 4 + 1] = (bf16)(acc[m][1][j] + b1);
                v1[(j - 2) * 4 + 2] = (bf16)(acc[m][2][j] + b2);
                v1[(j - 2) * 4 + 3] = (bf16)(acc[m][3][j] + b3);
            }
            bf16* o = XO + ((size_t)(rb0 + m * 4) * 512 + hcol) * 16;
            *(bf16x8*)(o) = v0;
            *(bf16x8*)(o + 8) = v1;
        }
    } else {
        float* Cb = bz ? P.cY : P.cM;
        bf16* Ho = bz ? (((t + 1) & 1) ? P.hY1 : P.hY0)
                      : (((t + 1) & 1) ? P.hM1 : P.hM0);
        const bf16* xw = bz ? P.xwY : P.xwM;
        const float* Wc2 = bz ? P.Wc2Y : P.Wc2M;
        f32x4 wcv0 = *(const f32x4*)(Wc2 + hcol * 12);
        f32x4 wcv1 = *(const f32x4*)(Wc2 + hcol * 12 + 4);
        f32x4 wcv2 = *(const f32x4*)(Wc2 + hcol * 12 + 8);
        const int ktc = jb >> 1;
        const int fqp = (jb & 1) * 2 + (fr >> 3);
        bf16* hob = Ho + (((size_t)((brow >> 4) + wr * 4) * 16 + ktc) * 64 + fqp * 16 +
                          fq * 4) * 8 + (fr & 7);
#pragma unroll
        for (int m = 0; m < 4; ++m) {
            const size_t co = ((size_t)(rb0 + m * 4) * 512 + hcol);
            const bf16* xp = xw + co * 16;
            bf16x8 xv0 = *(const bf16x8*)(xp);
            bf16x8 xv1 = *(const bf16x8*)(xp + 8);
            f32x4 cvm = *(const f32x4*)(Cb + co * 4);
            const int row0 = rowbase + m * 16;
            f32x4 cd[4];
#pragma unroll
            for (int j = 0; j < 4; ++j)
                cd[j] = *(const f32x4*)(P.condT4 + ((size_t)t * B_TOT + row0 + j) * 4);
            f32x4 cnew;
            bf16* hom = hob + (size_t)m * 16 * 64 * 8;
#pragma unroll
            for (int j = 0; j < 4; ++j) {
                float z[4];
#pragma unroll
                for (int g = 0; g < 4; ++g) {
                    float xwv = (j < 2) ? (float)xv0[j * 4 + g] : (float)xv1[(j - 2) * 4 + g];
                    z[g] = acc[m][g][j] + xwv + cd[j][0] * wcv0[g] + cd[j][1] * wcv1[g] +
                           cd[j][2] * wcv2[g];
                }
                float ii = fsigm(z[0]);
                float ff = fsigm(z[1]);
                float gg = ftanh(z[2]);
                float oo = fsigm(z[3]);
                float cn = ff * cvm[j] + ii * gg;
                cnew[j] = cn;
                hom[j * 8] = (bf16)(oo * ftanh(cn));
            }
            *(f32x4*)(Cb + co * 4) = cnew;
        }
    }
}

// heads item: 64 rows (4 waves x 16 rows), step th; reads h[(th+1)&1].
__device__ __forceinline__ void heads_item(const DecP& P, float* zbuf, int hb, int th,
                                           int rowOff) {
    const int tid = threadIdx.x, wave = tid >> 6, lane = tid & 63;
    const int fr = lane & 15, fq = lane >> 4;
    const int rbase = rowOff + hb * 64 + wave * 16;
    const int rg = rbase >> 4;
    const int a = (th + 1) & 1;
    const bf16* hm = a ? P.hM1 : P.hM0;
    const bf16* hy = a ? P.hY1 : P.hY0;

    f32x4 am0 = {0.f, 0.f, 0.f, 0.f}, am1 = {0.f, 0.f, 0.f, 0.f}, ay0 = {0.f, 0.f, 0.f, 0.f};

    for (int kt = 0; kt < 16; ++kt) {
        const size_t ao = ((size_t)(rg * 16 + kt) * 64 + lane) * 8;
        bf16x8 a0 = *(const bf16x8*)(hm + ao);
        bf16x8 y0 = *(const bf16x8*)(hy + ao);
        const int k0 = kt * 32;
        const size_t bo = (size_t)fr * DH + k0 + fq * 8;
        bf16x8 b0 = *(const bf16x8*)(P.WhmT + bo);
        bf16x8 b1 = *(const bf16x8*)(P.WhmT + bo + 16 * DH);
        bf16x8 yb = *(const bf16x8*)(P.WhyT + bo);
        am0 = MFMA16(a0, b0, am0);
        am1 = MFMA16(a0, b1, am1);
        ay0 = MFMA16(y0, yb, ay0);
    }

    float* zm = zbuf + wave * 768;  // [16][32]
    float* zy = zm + 512;           // [16][16]
#pragma unroll
    for (int j = 0; j < 4; ++j) {
        int rl = fq * 4 + j;
        zm[rl * 32 + fr] = am0[j] + P.tscm[th * 32 + fr];
        zm[rl * 32 + 16 + fr] = am1[j] + P.tscm[th * 32 + 16 + fr];
        zy[rl * 16 + fr] = ay0[j] + P.tscy[th * 16 + fr];
    }
    __syncthreads();

    const int r = lane & 15;
    const size_t grow = (size_t)rbase + r;
    if (lane < 16) {
        float z[30];
#pragma unroll
        for (int i = 0; i < 30; ++i) z[i] = zm[r * 32 + i];
        float* o = P.out + (grow * SEQ + th) * 30;
        float mx = z[0];
#pragma unroll
        for (int i = 1; i < 5; ++i) mx = fmaxf(mx, z[i]);
        float e[5], s = 0.f;
#pragma unroll
        for (int i = 0; i < 5; ++i) {
            e[i] = __expf(z[i] - mx);
            s += e[i];
        }
        float inv = __fdividef(1.f, s);
#pragma unroll
        for (int i = 0; i < 5; ++i) o[i] = e[i] * inv;
#pragma unroll
        for (int i = 5; i < 10; ++i) o[i] = z[i];
#pragma unroll
        for (int i = 10; i < 15; ++i) o[i] = __expf(z[i]);
#pragma unroll
        for (int i = 15; i < 20; ++i) o[i] = z[i];
#pragma unroll
        for (int i = 20; i < 25; ++i) o[i] = __expf(z[i]);
#pragma unroll
        for (int i = 25; i < 30; ++i) o[i] = ftanh(z[i]);
    } else if (lane < 32) {
        float z[15];
#pragma unroll
        for (int i = 0; i < 15; ++i) z[i] = zy[r * 16 + i];
        float* o = P.out + (size_t)B_TOT * SEQ * 30 + (grow * SEQ + th) * 15;
        float mx = z[0];
#pragma unroll
        for (int i = 1; i < 5; ++i) mx = fmaxf(mx, z[i]);
        float e[5], s = 0.f;
#pragma unroll
        for (int i = 0; i < 5; ++i) {
            e[i] = __expf(z[i] - mx);
            s += e[i];
        }
        float inv = __fdividef(1.f, s);
#pragma unroll
        for (int i = 0; i < 5; ++i) o[i] = e[i] * inv;
#pragma unroll
        for (int i = 5; i < 10; ++i) o[i] = z[i];
#pragma unroll
        for (int i = 10; i < 15; ++i) o[i] = __expf(z[i]);
    }
}

// t: -1 = MODE0 xw precompute (grid NG0, full batch);
// 0..SEQ-1 = LSTM step t on chunk rowOff + ride-along heads of step t-1;
// SEQ = heads of final step only (itemOff = NG1).
__global__ __launch_bounds__(256, 2) void step_kernel(DecP P, int t, int itemOff,
                                                      int rowOff, int ngemm) {
    __shared__ float zbuf[4 * 768];  // heads scratch, 12 KiB
    const int item = blockIdx.x + itemOff;
    if (item < ngemm) {
        if (t < 0)
            gemm_item<0>(P, item, 0, 0);
        else if (t < SEQ)
            gemm_item<1>(P, item, t, rowOff);
    } else {
        if (t >= 1) heads_item(P, zbuf, item - ngemm, t - 1, rowOff);
    }
}

// ---------------------------------------------------------------------------
extern "C" void kernel_launch(void* const* d_in, const int* in_sizes, int n_in,
                              void* d_out, int out_size, void* d_ws, size_t ws_size,
                              hipStream_t stream) {
    const float* cond = (const float*)d_in[0];
    const float* sh = (const float*)d_in[1];
    const float* sc = (const float*)d_in[2];
    const float* Wm = (const float*)d_in[3];
    const float* Um = (const float*)d_in[4];
    const float* bm = (const float*)d_in[5];
    const float* Whm = (const float*)d_in[6];
    const float* bhm = (const float*)d_in[7];
    const float* Wy = (const float*)d_in[8];
    const float* Uy = (const float*)d_in[9];
    const float* by_ = (const float*)d_in[10];
    const float* Why = (const float*)d_in[11];
    const float* bhy = (const float*)d_in[12];
    float* out = (float*)d_out;

    char* p = (char*)d_ws;
    auto take = [&](size_t bytes) {
        char* r = p;
        p += (bytes + 255) & ~(size_t)255;
        return r;
    };
    bf16* UtM = (bf16*)take((size_t)ZW * DH * 2);
    bf16* UtY = (bf16*)take((size_t)ZW * DH * 2);
    bf16* WtM = (bf16*)take((size_t)ZW * DH * 2);
    bf16* WtY = (bf16*)take((size_t)ZW * DH * 2);
    float* Wc2M = (float*)take(512 * 12 * 4);
    float* Wc2Y = (float*)take(512 * 12 * 4);
    bf16* WhmT = (bf16*)take(32 * DH * 2);
    bf16* WhyT = (bf16*)take(16 * DH * 2);
    float* tscm = (float*)take(SEQ * 32 * 4);
    float* tscy = (float*)take(SEQ * 16 * 4);
    float* condT4 = (float*)take((size_t)SEQ * B_TOT * 4 * 4);
    bf16* xwM = (bf16*)take((size_t)B_TOT * ZW * 2);
    bf16* xwY = (bf16*)take((size_t)B_TOT * ZW * 2);
    bf16* hM0 = (bf16*)take((size_t)B_TOT * DH * 2);
    bf16* hM1 = (bf16*)take((size_t)B_TOT * DH * 2);
    bf16* hY0 = (bf16*)take((size_t)B_TOT * DH * 2);
    bf16* hY1 = (bf16*)take((size_t)B_TOT * DH * 2);
    float* cMb = (float*)take((size_t)B_TOT * DH * 4);
    float* cYb = (float*)take((size_t)B_TOT * DH * 4);

    init_state<<<(B_TOT * DH) / 256, 256, 0, stream>>>(sh, hM0, hY0);
    build_c3<<<(B_TOT * DH) / 256, 256, 0, stream>>>(sc, cMb, cYb);
    reorder_weights<<<(4 * ZW * DH) / 256, 256, 0, stream>>>(Um, Uy, Wm, Wy, UtM, UtY, WtM, WtY);
    build_wc2<<<(2 * 512 * 12 + 255) / 256, 256, 0, stream>>>(Wm, Wy, Wc2M, Wc2Y);
    cond_transpose<<<(SEQ * B_TOT + 255) / 256, 256, 0, stream>>>(cond, condT4);
    build_heads<<<(32 * 512 + 16 * 512 + SEQ * 32 + SEQ * 16 + 255) / 256, 256, 0, stream>>>(
        Whm, bhm, Why, bhy, WhmT, WhyT, tscm, tscy);

    DecP P;
    P.hM0 = hM0;
    P.hM1 = hM1;
    P.hY0 = hY0;
    P.hY1 = hY1;
    P.UtM = UtM;
    P.UtY = UtY;
    P.WtM = WtM;
    P.WtY = WtY;
    P.xwM = xwM;
    P.xwY = xwY;
    P.Wc2M = Wc2M;
    P.Wc2Y = Wc2Y;
    P.bm = bm;
    P.by_ = by_;
    P.cM = cMb;
    P.cY = cYb;
    P.condT4 = condT4;
    P.WhmT = WhmT;
    P.WhyT = WhyT;
    P.tscm = tscm;
    P.tscy = tscy;
    P.out = out;

    // xw precompute over the full batch (one-time).
    step_kernel<<<NG0, 256, 0, stream>>>(P, -1, 0, 0, NG0);

    // Sequence per batch chunk: the chunk's xw/c/h working set (~171 MB)
    // stays resident in the 256MB L3 across its 50 steps.
    for (int ch = 0; ch < NCHUNK; ++ch) {
        const int rowOff = ch * CROWS;
        for (int t = 0; t < SEQ; ++t)
            step_kernel<<<NG1 + NH1, 256, 0, stream>>>(P, t, 0, rowOff, NG1);
        step_kernel<<<NH1, 256, 0, stream>>>(P, SEQ, NG1, rowOff, NG1);
    }
}

// Round 12
// 6495.775 us; speedup vs baseline: 3.0810x; 1.0471x over previous
//
#include <hip/hip_runtime.h>

typedef __bf16 bf16;
typedef __attribute__((ext_vector_type(8))) __bf16 bf16x8;
typedef __attribute__((ext_vector_type(4))) __bf16 bf16x4;
typedef __attribute__((ext_vector_type(4))) float f32x4;
typedef __attribute__((ext_vector_type(4))) int i32x4;

#define B_TOT 16384
#define SEQ 50
#define DH 512
#define ZW 2048  // 4*DH
#define NT 16    // K-tiles of 32 (K = 512)

// Batch chunking: rows are independent; 8192-row chunks keep the per-chunk
// working set (xw 64MB + c 67MB + h 32MB + U 8MB ~= 171MB) resident in the
// 256MB Infinity Cache across all 50 steps of the chunk.
#define NCHUNK 2
#define CROWS 8192
#define NG0 4096  // MODE0 items: 128 bx * 16 by * 2 bz (full batch)
#define NG1 2048  // MODE1 items: 64 bx * 16 by * 2 bz (one chunk)
#define NH1 128   // heads items per chunk (64 rows each)

#define MFMA16(a, b, c) __builtin_amdgcn_mfma_f32_16x16x32_bf16(a, b, c, 0, 0, 0)

__device__ __forceinline__ float fsigm(float x) {
    return __fdividef(1.0f, 1.0f + __expf(-x));
}
__device__ __forceinline__ float ftanh(float x) {
    float e = __expf(2.0f * x);
    return 1.0f - __fdividef(2.0f, e + 1.0f);
}

// ---------------------------------------------------------------------------
// Fragment layout (both GEMM operands):
//   frag[((rg*16 + kt)*64 + fq*16 + fr)]*8 + e <-> element [rg*16+fr][kt*32+fq*8+e]
// Strides: rg = 16384 B, kt = 1024 B, lane-slot = 16 B.
// ---------------------------------------------------------------------------

__global__ void init_state(const float* __restrict__ sh,
                           bf16* __restrict__ h0m, bf16* __restrict__ h0y) {
    size_t i = (size_t)blockIdx.x * 256 + threadIdx.x;
    int row = i >> 9, k = i & 511;
    size_t off = (((size_t)(row >> 4) * 16 + (k >> 5)) * 64 + ((k >> 3) & 3) * 16 +
                  (row & 15)) * 8 + (k & 7);
    bf16 hb = (bf16)sh[i];
    h0m[off] = hb;
    h0y[off] = hb;
}

// c3[row>>2][hcol][row&3] f32, duplicated into cM and cY.
__global__ void build_c3(const float* __restrict__ src,
                         float* __restrict__ dM, float* __restrict__ dY) {
    size_t i = (size_t)blockIdx.x * 256 + threadIdx.x;
    int row = i >> 9, hcol = i & 511;
    float v = src[i];
    size_t o = ((size_t)(row >> 2) * 512 + hcol) * 4 + (row & 3);
    dM[o] = v;
    dY[o] = v;
}

__device__ __forceinline__ int orig_col(int colp) {
    return ((colp >> 4) & 3) * 512 + ((colp >> 6) << 4) + (colp & 15);
}

// B-operands (U^T, W^T) in fragment layout.
__global__ void reorder_weights(const float* __restrict__ Um, const float* __restrict__ Uy,
                                const float* __restrict__ Wm, const float* __restrict__ Wy,
                                bf16* __restrict__ UtM, bf16* __restrict__ UtY,
                                bf16* __restrict__ WtM, bf16* __restrict__ WtY) {
    int idx = blockIdx.x * 256 + threadIdx.x;
    int which = idx >> 20;
    int r = idx & ((1 << 20) - 1);
    int colp = r >> 9, k = r & 511;
    int orig = orig_col(colp);
    const float* src = which == 0 ? Um : which == 1 ? Uy : which == 2 ? Wm : Wy;
    bf16* dst = which == 0 ? UtM : which == 1 ? UtY : which == 2 ? WtM : WtY;
    int cb = colp >> 4, fr = colp & 15;
    int kt = k >> 5, fq = (k >> 3) & 3, e = k & 7;
    int lane = fq * 16 + fr;
    dst[(((size_t)(cb * 16 + kt) * 64 + lane) << 3) + e] = (bf16)src[(size_t)k * ZW + orig];
}

// Wc2[hcol][r(3)][g(4)] f32
__global__ void build_wc2(const float* __restrict__ Wm, const float* __restrict__ Wy,
                          float* __restrict__ Wc2M, float* __restrict__ Wc2Y) {
    int idx = blockIdx.x * 256 + threadIdx.x;
    if (idx >= 2 * 512 * 12) return;
    int which = idx / 6144;
    int r2 = idx % 6144;
    int hcol = r2 / 12, rg = r2 % 12;
    int r = rg >> 2, g = rg & 3;
    const float* src = which ? Wy : Wm;
    float* dst = which ? Wc2Y : Wc2M;
    dst[hcol * 12 + rg] = src[(size_t)(512 + r) * ZW + g * 512 + hcol];
}

// condT4[t][row][4] f32
__global__ void cond_transpose(const float* __restrict__ cond, float* __restrict__ condT4) {
    int idx = blockIdx.x * 256 + threadIdx.x;
    if (idx >= SEQ * B_TOT) return;
    int t = idx / B_TOT, row = idx % B_TOT;
    const float* s = cond + ((size_t)row * SEQ + t) * 3;
    f32x4 v = {s[0], s[1], s[2], 0.f};
    *(f32x4*)(condT4 + (size_t)idx * 4) = v;
}

__global__ void build_heads(const float* __restrict__ Whm, const float* __restrict__ bhm,
                            const float* __restrict__ Why, const float* __restrict__ bhy,
                            bf16* __restrict__ WhmT, bf16* __restrict__ WhyT,
                            float* __restrict__ tscm, float* __restrict__ tscy) {
    int i = blockIdx.x * 256 + threadIdx.x;
    const int N1 = 32 * 512, N2 = 16 * 512, N3 = SEQ * 32, N4 = SEQ * 16;
    if (i < N1) {
        int n = i >> 9, k = i & 511;
        WhmT[i] = (bf16)(n < 30 ? Whm[k * 30 + n] : 0.f);
    } else if (i < N1 + N2) {
        int j = i - N1;
        int n = j >> 9, k = j & 511;
        WhyT[j] = (bf16)(n < 15 ? Why[k * 15 + n] : 0.f);
    } else if (i < N1 + N2 + N3) {
        int j = i - (N1 + N2);
        int tt = j >> 5, col = j & 31;
        float v = 0.f;
        if (col < 30) {
            v = bhm[col];
            for (int s = 0; s <= tt; ++s) v += Whm[(512 + s) * 30 + col];
        }
        tscm[j] = v;
    } else if (i < N1 + N2 + N3 + N4) {
        int j = i - (N1 + N2 + N3);
        int tt = j >> 4, col = j & 15;
        float v = 0.f;
        if (col < 15) {
            v = bhy[col];
            for (int s = 0; s <= tt; ++s) v += Why[(512 + s) * 15 + col];
        }
        tscy[j] = v;
    }
}

// ---------------------------------------------------------------------------
// Decoder work items.
// ---------------------------------------------------------------------------

struct DecP {
    bf16 *hM0, *hM1, *hY0, *hY1;
    const bf16 *UtM, *UtY, *WtM, *WtY;
    bf16 *xwM, *xwY;
    const float *Wc2M, *Wc2Y, *bm, *by_;
    float *cM, *cY;
    const float* condT4;
    const bf16 *WhmT, *WhyT;
    const float *tscm, *tscy;
    float* out;
};

#define WAIT_VM(n)                                                  \
    do {                                                            \
        asm volatile("s_waitcnt vmcnt(" #n ")" ::: "memory");       \
        __builtin_amdgcn_sched_barrier(0);                          \
    } while (0)

// gemm item: 128x128 tile, BK=32, 4 waves (2x2), no LDS, no barriers.
// DEPTH-2 register pipeline (2 fragment banks, 16 loads in flight,
// steady-state vmcnt(8)) -- keeps VGPR ~140 incl. acc so 3 waves/SIMD fit.
template <int MODE>
__device__ __forceinline__ void gemm_item(const DecP& P, int item, int t, int rowOff) {
    const int tid = threadIdx.x;
    const int wave = tid >> 6, lane = tid & 63;
    // XCD-aware swizzle: each XCD owns a contiguous bx band, by iterates within.
    const int bz = (MODE == 0) ? (item >> 11) : (item >> 10);
    const int lin = (MODE == 0) ? (item & 2047) : (item & 1023);
    const int xcd = lin & 7, jj2 = lin >> 3;
    const int bx = (MODE == 0) ? (xcd * 16 + (jj2 >> 4)) : (xcd * 8 + (jj2 >> 4));
    const int by = jj2 & 15;
    const int brow = rowOff + bx * 128;

    const bf16* A;
    const bf16* Bt;
    if (MODE == 0) {
        A = P.hM0;
        Bt = bz ? P.WtY : P.WtM;
    } else {
        A = bz ? ((t & 1) ? P.hY1 : P.hY0) : ((t & 1) ? P.hM1 : P.hM0);
        Bt = bz ? P.UtY : P.UtM;
    }

    const int fr = lane & 15, fq = lane >> 4;
    const int wr = wave >> 1, wc = wave & 1;

    const uint64_t abase =
        (uint64_t)(const char*)A + (uint64_t)((brow >> 4) + wr * 4) * 16384 + lane * 16;
    const uint64_t bbase =
        (uint64_t)(const char*)Bt + (uint64_t)(by * 8 + wc * 4) * 16384 + lane * 16;

    f32x4 acc[4][4];
#pragma unroll
    for (int m = 0; m < 4; ++m)
#pragma unroll
        for (int n = 0; n < 4; ++n) acc[m][n] = (f32x4){0.f, 0.f, 0.f, 0.f};

    i32x4 afr[2][4], bfr[2][4];

#define AGLOAD(bank, kts)                                                         \
    do {                                                                          \
        uint64_t _a = abase + (uint64_t)(kts) * 1024;                             \
        asm volatile("global_load_dwordx4 %0, %1, off"                            \
                     : "=&v"(afr[bank][0]) : "v"(_a) : "memory");                 \
        asm volatile("global_load_dwordx4 %0, %1, off"                            \
                     : "=&v"(afr[bank][1]) : "v"(_a + 16384) : "memory");         \
        asm volatile("global_load_dwordx4 %0, %1, off"                            \
                     : "=&v"(afr[bank][2]) : "v"(_a + 32768) : "memory");         \
        asm volatile("global_load_dwordx4 %0, %1, off"                            \
                     : "=&v"(afr[bank][3]) : "v"(_a + 49152) : "memory");         \
    } while (0)
#define BGLOAD(bank, kts)                                                         \
    do {                                                                          \
        uint64_t _b = bbase + (uint64_t)(kts) * 1024;                             \
        asm volatile("global_load_dwordx4 %0, %1, off"                            \
                     : "=&v"(bfr[bank][0]) : "v"(_b) : "memory");                 \
        asm volatile("global_load_dwordx4 %0, %1, off"                            \
                     : "=&v"(bfr[bank][1]) : "v"(_b + 16384) : "memory");         \
        asm volatile("global_load_dwordx4 %0, %1, off"                            \
                     : "=&v"(bfr[bank][2]) : "v"(_b + 32768) : "memory");         \
        asm volatile("global_load_dwordx4 %0, %1, off"                            \
                     : "=&v"(bfr[bank][3]) : "v"(_b + 49152) : "memory");         \
    } while (0)

    // prologue: tiles 0 and 1 in flight (16 loads)
    AGLOAD(0, 0);
    BGLOAD(0, 0);
    AGLOAD(1, 1);
    BGLOAD(1, 1);

#pragma unroll
    for (int kt = 0; kt < NT; ++kt) {
        if (kt < NT - 1) {
            WAIT_VM(8);  // retire tile kt's 8 loads; tile kt+1 stays in flight
        } else {
            WAIT_VM(0);
        }
        __builtin_amdgcn_s_setprio(1);
#pragma unroll
        for (int m = 0; m < 4; ++m)
#pragma unroll
            for (int n = 0; n < 4; ++n)
                acc[m][n] = MFMA16(__builtin_bit_cast(bf16x8, afr[kt & 1][m]),
                                   __builtin_bit_cast(bf16x8, bfr[kt & 1][n]), acc[m][n]);
        __builtin_amdgcn_s_setprio(0);
        __builtin_amdgcn_sched_barrier(0);
        if (kt + 2 < NT) {
            AGLOAD(kt & 1, kt + 2);
            BGLOAD(kt & 1, kt + 2);
        }
    }
#undef AGLOAD
#undef BGLOAD

    const int jb = by * 2 + wc;     // 0..31
    const int hcol = jb * 16 + fr;  // 0..511
    const int rowbase = brow + wr * 64 + fq * 4;
    const int rb0 = (rowbase >> 2);

    if (MODE == 0) {
        const float* bias = bz ? P.by_ : P.bm;
        bf16* XO = bz ? P.xwY : P.xwM;
        float b0 = bias[hcol], b1 = bias[512 + hcol], b2 = bias[1024 + hcol],
              b3 = bias[1536 + hcol];
#pragma unroll
        for (int m = 0; m < 4; ++m) {
            bf16x8 v0, v1;
#pragma unroll
            for (int j = 0; j < 2; ++j) {
                v0[j * 4 + 0] = (bf16)(acc[m][0][j] + b0);
                v0[j * 4 + 1] = (bf16)(acc[m][1][j] + b1);
                v0[j * 4 + 2] = (bf16)(acc[m][2][j] + b2);
                v0[j * 4 + 3] = (bf16)(acc[m][3][j] + b3);
            }
#pragma unroll
            for (int j = 2; j < 4; ++j) {
                v1[(j - 2) * 4 + 0] = (bf16)(acc[m][0][j] + b0);
                v1[(j - 2) * 4 + 1] = (bf16)(acc[m][1][j] + b1);
                v1[(j - 2) * 4 + 2] = (bf16)(acc[m][2][j] + b2);
                v1[(j - 2) * 4 + 3] = (bf16)(acc[m][3][j] + b3);
            }
            bf16* o = XO + ((size_t)(rb0 + m * 4) * 512 + hcol) * 16;
            *(bf16x8*)(o) = v0;
            *(bf16x8*)(o + 8) = v1;
        }
    } else {
        float* Cb = bz ? P.cY : P.cM;
        bf16* Ho = bz ? (((t + 1) & 1) ? P.hY1 : P.hY0)
                      : (((t + 1) & 1) ? P.hM1 : P.hM0);
        const bf16* xw = bz ? P.xwY : P.xwM;
        const float* Wc2 = bz ? P.Wc2Y : P.Wc2M;
        f32x4 wcv0 = *(const f32x4*)(Wc2 + hcol * 12);
        f32x4 wcv1 = *(const f32x4*)(Wc2 + hcol * 12 + 4);
        f32x4 wcv2 = *(const f32x4*)(Wc2 + hcol * 12 + 8);
        const int ktc = jb >> 1;
        const int fqp = (jb & 1) * 2 + (fr >> 3);
        bf16* hob = Ho + (((size_t)((brow >> 4) + wr * 4) * 16 + ktc) * 64 + fqp * 16 +
                          fq * 4) * 8 + (fr & 7);
#pragma unroll
        for (int m = 0; m < 4; ++m) {
            const size_t co = ((size_t)(rb0 + m * 4) * 512 + hcol);
            const bf16* xp = xw + co * 16;
            bf16x8 xv0 = *(const bf16x8*)(xp);
            bf16x8 xv1 = *(const bf16x8*)(xp + 8);
            f32x4 cvm = *(const f32x4*)(Cb + co * 4);
            const int row0 = rowbase + m * 16;
            f32x4 cd[4];
#pragma unroll
            for (int j = 0; j < 4; ++j)
                cd[j] = *(const f32x4*)(P.condT4 + ((size_t)t * B_TOT + row0 + j) * 4);
            f32x4 cnew;
            bf16* hom = hob + (size_t)m * 16 * 64 * 8;
#pragma unroll
            for (int j = 0; j < 4; ++j) {
                float z[4];
#pragma unroll
                for (int g = 0; g < 4; ++g) {
                    float xwv = (j < 2) ? (float)xv0[j * 4 + g] : (float)xv1[(j - 2) * 4 + g];
                    z[g] = acc[m][g][j] + xwv + cd[j][0] * wcv0[g] + cd[j][1] * wcv1[g] +
                           cd[j][2] * wcv2[g];
                }
                float ii = fsigm(z[0]);
                float ff = fsigm(z[1]);
                float gg = ftanh(z[2]);
                float oo = fsigm(z[3]);
                float cn = ff * cvm[j] + ii * gg;
                cnew[j] = cn;
                hom[j * 8] = (bf16)(oo * ftanh(cn));
            }
            *(f32x4*)(Cb + co * 4) = cnew;
        }
    }
}

// heads item: 64 rows (4 waves x 16 rows), step th; reads h[(th+1)&1].
__device__ __forceinline__ void heads_item(const DecP& P, float* zbuf, int hb, int th,
                                           int rowOff) {
    const int tid = threadIdx.x, wave = tid >> 6, lane = tid & 63;
    const int fr = lane & 15, fq = lane >> 4;
    const int rbase = rowOff + hb * 64 + wave * 16;
    const int rg = rbase >> 4;
    const int a = (th + 1) & 1;
    const bf16* hm = a ? P.hM1 : P.hM0;
    const bf16* hy = a ? P.hY1 : P.hY0;

    f32x4 am0 = {0.f, 0.f, 0.f, 0.f}, am1 = {0.f, 0.f, 0.f, 0.f}, ay0 = {0.f, 0.f, 0.f, 0.f};

    for (int kt = 0; kt < 16; ++kt) {
        const size_t ao = ((size_t)(rg * 16 + kt) * 64 + lane) * 8;
        bf16x8 a0 = *(const bf16x8*)(hm + ao);
        bf16x8 y0 = *(const bf16x8*)(hy + ao);
        const int k0 = kt * 32;
        const size_t bo = (size_t)fr * DH + k0 + fq * 8;
        bf16x8 b0 = *(const bf16x8*)(P.WhmT + bo);
        bf16x8 b1 = *(const bf16x8*)(P.WhmT + bo + 16 * DH);
        bf16x8 yb = *(const bf16x8*)(P.WhyT + bo);
        am0 = MFMA16(a0, b0, am0);
        am1 = MFMA16(a0, b1, am1);
        ay0 = MFMA16(y0, yb, ay0);
    }

    float* zm = zbuf + wave * 768;  // [16][32]
    float* zy = zm + 512;           // [16][16]
#pragma unroll
    for (int j = 0; j < 4; ++j) {
        int rl = fq * 4 + j;
        zm[rl * 32 + fr] = am0[j] + P.tscm[th * 32 + fr];
        zm[rl * 32 + 16 + fr] = am1[j] + P.tscm[th * 32 + 16 + fr];
        zy[rl * 16 + fr] = ay0[j] + P.tscy[th * 16 + fr];
    }
    __syncthreads();

    const int r = lane & 15;
    const size_t grow = (size_t)rbase + r;
    if (lane < 16) {
        float z[30];
#pragma unroll
        for (int i = 0; i < 30; ++i) z[i] = zm[r * 32 + i];
        float* o = P.out + (grow * SEQ + th) * 30;
        float mx = z[0];
#pragma unroll
        for (int i = 1; i < 5; ++i) mx = fmaxf(mx, z[i]);
        float e[5], s = 0.f;
#pragma unroll
        for (int i = 0; i < 5; ++i) {
            e[i] = __expf(z[i] - mx);
            s += e[i];
        }
        float inv = __fdividef(1.f, s);
#pragma unroll
        for (int i = 0; i < 5; ++i) o[i] = e[i] * inv;
#pragma unroll
        for (int i = 5; i < 10; ++i) o[i] = z[i];
#pragma unroll
        for (int i = 10; i < 15; ++i) o[i] = __expf(z[i]);
#pragma unroll
        for (int i = 15; i < 20; ++i) o[i] = z[i];
#pragma unroll
        for (int i = 20; i < 25; ++i) o[i] = __expf(z[i]);
#pragma unroll
        for (int i = 25; i < 30; ++i) o[i] = ftanh(z[i]);
    } else if (lane < 32) {
        float z[15];
#pragma unroll
        for (int i = 0; i < 15; ++i) z[i] = zy[r * 16 + i];
        float* o = P.out + (size_t)B_TOT * SEQ * 30 + (grow * SEQ + th) * 15;
        float mx = z[0];
#pragma unroll
        for (int i = 1; i < 5; ++i) mx = fmaxf(mx, z[i]);
        float e[5], s = 0.f;
#pragma unroll
        for (int i = 0; i < 5; ++i) {
            e[i] = __expf(z[i] - mx);
            s += e[i];
        }
        float inv = __fdividef(1.f, s);
#pragma unroll
        for (int i = 0; i < 5; ++i) o[i] = e[i] * inv;
#pragma unroll
        for (int i = 5; i < 10; ++i) o[i] = z[i];
#pragma unroll
        for (int i = 10; i < 15; ++i) o[i] = __expf(z[i]);
    }
}

// t: -1 = MODE0 xw precompute (grid NG0, full batch);
// 0..SEQ-1 = LSTM step t on chunk rowOff + ride-along heads of step t-1;
// SEQ = heads of final step only (itemOff = NG1).
__global__ __launch_bounds__(256, 3) void step_kernel(DecP P, int t, int itemOff,
                                                      int rowOff, int ngemm) {
    __shared__ float zbuf[4 * 768];  // heads scratch, 12 KiB
    const int item = blockIdx.x + itemOff;
    if (item < ngemm) {
        if (t < 0)
            gemm_item<0>(P, item, 0, 0);
        else if (t < SEQ)
            gemm_item<1>(P, item, t, rowOff);
    } else {
        if (t >= 1) heads_item(P, zbuf, item - ngemm, t - 1, rowOff);
    }
}

// ---------------------------------------------------------------------------
extern "C" void kernel_launch(void* const* d_in, const int* in_sizes, int n_in,
                              void* d_out, int out_size, void* d_ws, size_t ws_size,
                              hipStream_t stream) {
    const float* cond = (const float*)d_in[0];
    const float* sh = (const float*)d_in[1];
    const float* sc = (const float*)d_in[2];
    const float* Wm = (const float*)d_in[3];
    const float* Um = (const float*)d_in[4];
    const float* bm = (const float*)d_in[5];
    const float* Whm = (const float*)d_in[6];
    const float* bhm = (const float*)d_in[7];
    const float* Wy = (const float*)d_in[8];
    const float* Uy = (const float*)d_in[9];
    const float* by_ = (const float*)d_in[10];
    const float* Why = (const float*)d_in[11];
    const float* bhy = (const float*)d_in[12];
    float* out = (float*)d_out;

    char* p = (char*)d_ws;
    auto take = [&](size_t bytes) {
        char* r = p;
        p += (bytes + 255) & ~(size_t)255;
        return r;
    };
    bf16* UtM = (bf16*)take((size_t)ZW * DH * 2);
    bf16* UtY = (bf16*)take((size_t)ZW * DH * 2);
    bf16* WtM = (bf16*)take((size_t)ZW * DH * 2);
    bf16* WtY = (bf16*)take((size_t)ZW * DH * 2);
    float* Wc2M = (float*)take(512 * 12 * 4);
    float* Wc2Y = (float*)take(512 * 12 * 4);
    bf16* WhmT = (bf16*)take(32 * DH * 2);
    bf16* WhyT = (bf16*)take(16 * DH * 2);
    float* tscm = (float*)take(SEQ * 32 * 4);
    float* tscy = (float*)take(SEQ * 16 * 4);
    float* condT4 = (float*)take((size_t)SEQ * B_TOT * 4 * 4);
    bf16* xwM = (bf16*)take((size_t)B_TOT * ZW * 2);
    bf16* xwY = (bf16*)take((size_t)B_TOT * ZW * 2);
    bf16* hM0 = (bf16*)take((size_t)B_TOT * DH * 2);
    bf16* hM1 = (bf16*)take((size_t)B_TOT * DH * 2);
    bf16* hY0 = (bf16*)take((size_t)B_TOT * DH * 2);
    bf16* hY1 = (bf16*)take((size_t)B_TOT * DH * 2);
    float* cMb = (float*)take((size_t)B_TOT * DH * 4);
    float* cYb = (float*)take((size_t)B_TOT * DH * 4);

    init_state<<<(B_TOT * DH) / 256, 256, 0, stream>>>(sh, hM0, hY0);
    build_c3<<<(B_TOT * DH) / 256, 256, 0, stream>>>(sc, cMb, cYb);
    reorder_weights<<<(4 * ZW * DH) / 256, 256, 0, stream>>>(Um, Uy, Wm, Wy, UtM, UtY, WtM, WtY);
    build_wc2<<<(2 * 512 * 12 + 255) / 256, 256, 0, stream>>>(Wm, Wy, Wc2M, Wc2Y);
    cond_transpose<<<(SEQ * B_TOT + 255) / 256, 256, 0, stream>>>(cond, condT4);
    build_heads<<<(32 * 512 + 16 * 512 + SEQ * 32 + SEQ * 16 + 255) / 256, 256, 0, stream>>>(
        Whm, bhm, Why, bhy, WhmT, WhyT, tscm, tscy);

    DecP P;
    P.hM0 = hM0;
    P.hM1 = hM1;
    P.hY0 = hY0;
    P.hY1 = hY1;
    P.UtM = UtM;
    P.UtY = UtY;
    P.WtM = WtM;
    P.WtY = WtY;
    P.xwM = xwM;
    P.xwY = xwY;
    P.Wc2M = Wc2M;
    P.Wc2Y = Wc2Y;
    P.bm = bm;
    P.by_ = by_;
    P.cM = cMb;
    P.cY = cYb;
    P.condT4 = condT4;
    P.WhmT = WhmT;
    P.WhyT = WhyT;
    P.tscm = tscm;
    P.tscy = tscy;
    P.out = out;

    // xw precompute over the full batch (one-time).
    step_kernel<<<NG0, 256, 0, stream>>>(P, -1, 0, 0, NG0);

    // Sequence per batch chunk: the chunk's xw/c/h working set (~171 MB)
    // stays resident in the 256MB L3 across its 50 steps.
    for (int ch = 0; ch < NCHUNK; ++ch) {
        const int rowOff = ch * CROWS;
        for (int t = 0; t < SEQ; ++t)
            step_kernel<<<NG1 + NH1, 256, 0, stream>>>(P, t, 0, rowOff, NG1);
        step_kernel<<<NH1, 256, 0, stream>>>(P, SEQ, NG1, rowOff, NG1);
    }
}